// Round 2
// baseline (1270.502 us; speedup 1.0000x reference)
//
#include <hip/hip_runtime.h>
#include <hip/hip_bf16.h>
#include <cstdint>
#include <cstddef>

#define DF 128
#define NEG 0.01f

__global__ void k_sentinel(float* out, int n) {
    int i = blockIdx.x * blockDim.x + threadIdx.x;
    if (i < n) out[i] = 12345.0f;
}

__global__ void k_deg(const int* __restrict__ row, const int* __restrict__ col,
                      const float* __restrict__ w,
                      float* __restrict__ cdeg, int* __restrict__ rcnt, int E) {
    int e = blockIdx.x * blockDim.x + threadIdx.x;
    if (e < E) {
        atomicAdd(&cdeg[col[e]], w[e]);
        atomicAdd(&rcnt[row[e]], 1);
    }
}

__global__ void k_derive(const float* __restrict__ cdeg, float* __restrict__ dg,
                         float* __restrict__ dinv, int N) {
    int n = blockIdx.x * blockDim.x + threadIdx.x;
    if (n < N) {
        float c = cdeg[n];
        dg[n] = rsqrtf(c + 1.0f);
        dinv[n] = 1.0f / c;
    }
}

__global__ void __launch_bounds__(1024) k_scan(const int* __restrict__ cnt,
                                               int* __restrict__ rp, int* __restrict__ cur, int N) {
    __shared__ int s[1024];
    int t = threadIdx.x;
    int chunk = (N + 1023) >> 10;
    int b = t * chunk;
    int e = b + chunk; if (e > N) e = N;
    if (b > N) b = N;
    int sum = 0;
    for (int i = b; i < e; ++i) sum += cnt[i];
    s[t] = sum; __syncthreads();
    for (int off = 1; off < 1024; off <<= 1) {
        int v = (t >= off) ? s[t - off] : 0;
        __syncthreads();
        s[t] += v;
        __syncthreads();
    }
    int pre = (t == 0) ? 0 : s[t - 1];
    for (int i = b; i < e; ++i) { rp[i] = pre; cur[i] = pre; pre += cnt[i]; }
    if (t == 0) rp[N] = s[1023];
}

__global__ void k_scatter(const int* __restrict__ row, const int* __restrict__ col,
                          const float* __restrict__ w,
                          const float* __restrict__ dg, const float* __restrict__ dinv,
                          int* __restrict__ cur, int* __restrict__ ci,
                          float* __restrict__ cwg, float* __restrict__ cws, int E) {
    int e = blockIdx.x * blockDim.x + threadIdx.x;
    if (e < E) {
        int r = row[e], c = col[e];
        float wf = w[e];
        int p = atomicAdd(&cur[r], 1);
        ci[p] = c;
        cwg[p] = wf * dg[c];
        cws[p] = wf * dinv[c];
    }
}

// GCN step: xn = (SPMM(cwg, x) + dg[r]*x[r]) * dg[r]   (raw output; leaky applied later)
__global__ void __launch_bounds__(128) k_gcn(const int* __restrict__ rp, const int* __restrict__ ci,
                                             const float* __restrict__ cwg,
                                             const float* __restrict__ x,
                                             const float* __restrict__ dg,
                                             float* __restrict__ xn) {
    int r = blockIdx.x, d = threadIdx.x;
    int s = rp[r], e = rp[r + 1];
    float acc = 0.f;
    for (int j = s; j < e; ++j) acc += cwg[j] * x[ci[j] * DF + d];
    int idx = r * DF + d;
    float g = dg[r];
    xn[idx] = (acc + g * x[idx]) * g;
}

// Scattering step: fpn = 0.5*fpc + 0.5*SPMM(cws, fpc); optionally hs = |fpc-fpn|^m
__global__ void __launch_bounds__(128) k_sct(const int* __restrict__ rp, const int* __restrict__ ci,
                                             const float* __restrict__ cws,
                                             const float* __restrict__ fpc,
                                             float* __restrict__ fpn, float* __restrict__ hs,
                                             const int* __restrict__ mom) {
    int r = blockIdx.x, d = threadIdx.x;
    int s = rp[r], e = rp[r + 1];
    float acc = 0.f;
    for (int j = s; j < e; ++j) acc += cws[j] * fpc[ci[j] * DF + d];
    int idx = r * DF + d;
    float prev = fpc[idx];
    float nv = 0.5f * prev + 0.5f * acc;
    fpn[idx] = nv;
    if (hs != nullptr) {
        float dd = fabsf(prev - nv);
        int raw = mom[0];
        int m = (raw == 1 || raw == 16256 || raw == 1065353216) ? 1
              : (raw > 1 && raw < 16) ? raw : 1;
        hs[idx] = (m == 1) ? dd : powf(dd, (float)m);
    }
}

__global__ void __launch_bounds__(128) k_attn(const float* __restrict__ X,
                                              const float* __restrict__ g1,
                                              const float* __restrict__ g2,
                                              const float* __restrict__ g3,
                                              const float* __restrict__ s1,
                                              const float* __restrict__ s2,
                                              const float* __restrict__ s3,
                                              const float* __restrict__ a,
                                              float* __restrict__ hp) {
    int n = blockIdx.x, d = threadIdx.x;
    int idx = n * DF + d;
    float hv[6];
    // GCN channels get leaky_relu here (g* hold raw GCN outputs)
    float gv1 = g1[idx], gv2 = g2[idx], gv3 = g3[idx];
    hv[0] = gv1 > 0.f ? gv1 : NEG * gv1;
    hv[1] = gv2 > 0.f ? gv2 : NEG * gv2;
    hv[2] = gv3 > 0.f ? gv3 : NEG * gv3;
    hv[3] = s1[idx]; hv[4] = s2[idx]; hv[5] = s3[idx];
    float xv = X[idx];
    float a1 = a[d], a2 = a[DF + d];
    float part[7];
    part[0] = fmaxf(xv, 0.f) * a1;
#pragma unroll
    for (int c = 0; c < 6; ++c) part[c + 1] = fmaxf(hv[c], 0.f) * a2;
#pragma unroll
    for (int k = 0; k < 7; ++k) {
        float v = part[k];
#pragma unroll
        for (int off = 32; off > 0; off >>= 1) v += __shfl_down(v, off, 64);
        part[k] = v;
    }
    __shared__ float sw[2][7];
    int wid = d >> 6, lane = d & 63;
    if (lane == 0) {
#pragma unroll
        for (int k = 0; k < 7; ++k) sw[wid][k] = part[k];
    }
    __syncthreads();
    float base = sw[0][0] + sw[1][0];
    float ev[6];
    float mx = -1e30f;
#pragma unroll
    for (int c = 0; c < 6; ++c) { ev[c] = base + sw[0][c + 1] + sw[1][c + 1]; mx = fmaxf(mx, ev[c]); }
    float ssum = 0.f;
#pragma unroll
    for (int c = 0; c < 6; ++c) { ev[c] = __expf(ev[c] - mx); ssum += ev[c]; }
    float inv = 1.f / ssum;
    float acc = 0.f;
#pragma unroll
    for (int c = 0; c < 6; ++c) acc += ev[c] * hv[c];
    hp[idx] = acc * inv * (1.0f / 6.0f);
}

__global__ void k_tw(const float* __restrict__ w, float* __restrict__ wt) {
    int i = blockIdx.x * blockDim.x + threadIdx.x;
    if (i < DF * DF) {
        int o = i >> 7, k = i & 127;
        wt[k * DF + o] = w[i];
    }
}

__global__ void __launch_bounds__(128) k_mlp1(const float* __restrict__ in, const float* __restrict__ wt,
                                              const float* __restrict__ bias,
                                              float* __restrict__ out) {
    int r = blockIdx.x, o = threadIdx.x;
    const float* inr = in + r * DF;
    float acc = bias[o];
#pragma unroll 8
    for (int k = 0; k < DF; ++k) acc = fmaf(inr[k], wt[k * DF + o], acc);
    out[r * DF + o] = acc > 0.f ? acc : NEG * acc;
}

__global__ void __launch_bounds__(128) k_mlp2(const float* __restrict__ in, const float* __restrict__ wt,
                                              const float* __restrict__ bias,
                                              float* __restrict__ out) {
    int r = blockIdx.x, o = threadIdx.x;
    const float* inr = in + r * DF;
    float acc = bias[o];
#pragma unroll 8
    for (int k = 0; k < DF; ++k) acc = fmaf(inr[k], wt[k * DF + o], acc);
    out[r * DF + o] = acc > 0.f ? acc : NEG * acc;
}

extern "C" void kernel_launch(void* const* d_in, const int* in_sizes, int n_in,
                              void* d_out, int out_size, void* d_ws, size_t ws_size,
                              hipStream_t stream) {
    const float* X  = (const float*)d_in[0];
    const int*   ei = (const int*)d_in[1];
    const float* ew = (const float*)d_in[2];
    const float* W1 = (const float*)d_in[3];
    const float* b1 = (const float*)d_in[4];
    const float* W2 = (const float*)d_in[5];
    const float* b2 = (const float*)d_in[6];
    const float* a  = (const float*)d_in[7];
    const int*  mom = (const int*)d_in[8];

    const int N = in_sizes[0] / DF;
    const int E = in_sizes[2];
    const int* row = ei;
    const int* col = ei + E;
    const size_t ND = (size_t)N * DF;

    char* p = (char*)d_ws;
    auto alloc = [&](size_t bytes) -> void* {
        char* r = p;
        p += (bytes + 255) & ~(size_t)255;
        return (void*)r;
    };
    float* G1 = (float*)alloc(ND * 4);
    float* G2 = (float*)alloc(ND * 4);
    float* G3 = (float*)alloc(ND * 4);
    float* S1 = (float*)alloc(ND * 4);
    float* S2 = (float*)alloc(ND * 4);
    float* S3 = (float*)alloc(ND * 4);
    float* P  = (float*)alloc(ND * 4);
    float* Q  = (float*)alloc(ND * 4);
    float* cdeg = (float*)alloc((size_t)N * 4);
    int*   rcnt = (int*)alloc((size_t)N * 4);
    float* dg   = (float*)alloc((size_t)N * 4);
    float* dinv = (float*)alloc((size_t)N * 4);
    int*   rp   = (int*)alloc((size_t)(N + 1) * 4);
    int*   cur  = (int*)alloc((size_t)N * 4);
    int*   ci   = (int*)alloc((size_t)E * 4);
    float* cwg  = (float*)alloc((size_t)E * 4);
    float* cws  = (float*)alloc((size_t)E * 4);
    float* Wt1  = (float*)alloc((size_t)DF * DF * 4);
    float* Wt2  = (float*)alloc((size_t)DF * DF * 4);

    if ((size_t)(p - (char*)d_ws) > ws_size) {
        // Workspace too small — unmistakable sentinel for diagnosability.
        k_sentinel<<<(out_size + 255) / 256, 256, 0, stream>>>((float*)d_out, out_size);
        return;
    }

    hipMemsetAsync(cdeg, 0, (size_t)N * 4, stream);
    hipMemsetAsync(rcnt, 0, (size_t)N * 4, stream);

    int eb = (E + 255) / 256;
    k_deg<<<eb, 256, 0, stream>>>(row, col, ew, cdeg, rcnt, E);
    k_derive<<<(N + 255) / 256, 256, 0, stream>>>(cdeg, dg, dinv, N);
    k_scan<<<1, 1024, 0, stream>>>(rcnt, rp, cur, N);
    k_scatter<<<eb, 256, 0, stream>>>(row, col, ew, dg, dinv, cur, ci, cwg, cws, E);

    // GCN tower (raw outputs; leaky fused into attention)
    k_gcn<<<N, DF, 0, stream>>>(rp, ci, cwg, X,  dg, G1);
    k_gcn<<<N, DF, 0, stream>>>(rp, ci, cwg, G1, dg, G2);
    k_gcn<<<N, DF, 0, stream>>>(rp, ci, cwg, G2, dg, G3);

    // Scattering tower: fp1=step(X)->P; fp2=step(P)->Q,S1; fp3=step(Q)->P,S2; fp4=step(P)->Q,S3
    k_sct<<<N, DF, 0, stream>>>(rp, ci, cws, X, P, (float*)nullptr, mom);
    k_sct<<<N, DF, 0, stream>>>(rp, ci, cws, P, Q, S1, mom);
    k_sct<<<N, DF, 0, stream>>>(rp, ci, cws, Q, P, S2, mom);
    k_sct<<<N, DF, 0, stream>>>(rp, ci, cws, P, Q, S3, mom);

    // Attention -> h_prime (f32) into P
    k_attn<<<N, DF, 0, stream>>>(X, G1, G2, G3, S1, S2, S3, a, P);

    // MLP
    k_tw<<<(DF * DF + 255) / 256, 256, 0, stream>>>(W1, Wt1);
    k_tw<<<(DF * DF + 255) / 256, 256, 0, stream>>>(W2, Wt2);
    k_mlp1<<<N, DF, 0, stream>>>(P, Wt1, b1, Q);
    k_mlp2<<<N, DF, 0, stream>>>(Q, Wt2, b2, (float*)d_out);
}

// Round 3
// 937.051 us; speedup vs baseline: 1.3559x; 1.3559x over previous
//
#include <hip/hip_runtime.h>
#include <hip/hip_bf16.h>
#include <cstdint>
#include <cstddef>

#define DF 128
#define NEG 0.01f

struct f2 { float x, y; };
static __device__ __forceinline__ f2 ld2(const float* p) { return *(const f2*)p; }
static __device__ __forceinline__ void st2(float* p, f2 v) { *(f2*)p = v; }

__global__ void k_sentinel(float* out, int n) {
    int i = blockIdx.x * blockDim.x + threadIdx.x;
    if (i < n) out[i] = 12345.0f;
}

__global__ void k_deg(const int* __restrict__ row, const int* __restrict__ col,
                      const float* __restrict__ w,
                      float* __restrict__ cdeg, int* __restrict__ rcnt, int E) {
    int e = blockIdx.x * blockDim.x + threadIdx.x;
    if (e < E) {
        atomicAdd(&cdeg[col[e]], w[e]);
        atomicAdd(&rcnt[row[e]], 1);
    }
}

__global__ void k_derive(const float* __restrict__ cdeg, float* __restrict__ dg,
                         float* __restrict__ dinv, int N) {
    int n = blockIdx.x * blockDim.x + threadIdx.x;
    if (n < N) {
        float c = cdeg[n];
        dg[n] = rsqrtf(c + 1.0f);
        dinv[n] = 1.0f / c;
    }
}

// ---- device-wide exclusive scan over rcnt, 3 small kernels ----
__global__ void __launch_bounds__(256) k_scan1(const int* __restrict__ cnt,
                                               int* __restrict__ pre,
                                               int* __restrict__ bsum, int N) {
    int t = threadIdx.x;
    int base = blockIdx.x * 1024 + t * 4;
    int v0 = 0, v1 = 0, v2 = 0, v3 = 0;
    if (base + 3 < N) {
        int4 q = *(const int4*)(cnt + base);
        v0 = q.x; v1 = q.y; v2 = q.z; v3 = q.w;
    } else {
        if (base     < N) v0 = cnt[base];
        if (base + 1 < N) v1 = cnt[base + 1];
        if (base + 2 < N) v2 = cnt[base + 2];
        if (base + 3 < N) v3 = cnt[base + 3];
    }
    int tt = v0 + v1 + v2 + v3;
    __shared__ int s[256];
    s[t] = tt; __syncthreads();
    for (int off = 1; off < 256; off <<= 1) {
        int v = (t >= off) ? s[t - off] : 0;
        __syncthreads();
        s[t] += v;
        __syncthreads();
    }
    int ex = (t == 0) ? 0 : s[t - 1];
    if (base     < N) pre[base]     = ex;
    if (base + 1 < N) pre[base + 1] = ex + v0;
    if (base + 2 < N) pre[base + 2] = ex + v0 + v1;
    if (base + 3 < N) pre[base + 3] = ex + v0 + v1 + v2;
    if (t == 255) bsum[blockIdx.x] = s[255];
}

__global__ void k_scan2(int* __restrict__ bsum, int B) {
    if (threadIdx.x == 0 && blockIdx.x == 0) {
        int run = 0;
        for (int i = 0; i < B; ++i) { int v = bsum[i]; bsum[i] = run; run += v; }
        bsum[B] = run;
    }
}

__global__ void __launch_bounds__(256) k_scan3(const int* __restrict__ bsum,
                                               int* __restrict__ rp, int* __restrict__ cur,
                                               int N, int B) {
    int i = blockIdx.x * 256 + threadIdx.x;
    if (i < N) {
        int v = rp[i] + bsum[i >> 10];
        rp[i] = v;
        cur[i] = v;
    }
    if (i == 0) rp[N] = bsum[B];
}

__global__ void k_scatter(const int* __restrict__ row, const int* __restrict__ col,
                          const float* __restrict__ w,
                          const float* __restrict__ dg, const float* __restrict__ dinv,
                          int* __restrict__ cur, int* __restrict__ ci,
                          float* __restrict__ cwg, float* __restrict__ cws, int E) {
    int e = blockIdx.x * blockDim.x + threadIdx.x;
    if (e < E) {
        int r = row[e], c = col[e];
        float wf = w[e];
        int p = atomicAdd(&cur[r], 1);
        ci[p] = c;
        cwg[p] = wf * dg[c];
        cws[p] = wf * dinv[c];
    }
}

// ---- fused SPMM tower kernels: one 64-lane wave per row, float2 per lane ----
// Step 1: GCN1 and SCT1 both gather X over the same edges — share every load.
__global__ void __launch_bounds__(256) k_step1(const int* __restrict__ rp, const int* __restrict__ ci,
                                               const float* __restrict__ cwg, const float* __restrict__ cws,
                                               const float* __restrict__ x,
                                               const float* __restrict__ dg,
                                               float* __restrict__ g1, float* __restrict__ fp1, int N) {
    int t = threadIdx.x;
    int lane = t & 63;
    int r = blockIdx.x * 4 + (t >> 6);
    if (r >= N) return;
    int s = rp[r], e = rp[r + 1];
    float agx = 0.f, agy = 0.f, asx = 0.f, asy = 0.f;
    for (int j = s; j < e; ++j) {
        int c = ci[j];
        float wg = cwg[j], ws = cws[j];
        f2 xv = ld2(x + c * DF + lane * 2);
        agx = fmaf(wg, xv.x, agx); agy = fmaf(wg, xv.y, agy);
        asx = fmaf(ws, xv.x, asx); asy = fmaf(ws, xv.y, asy);
    }
    float g = dg[r];
    f2 xr = ld2(x + r * DF + lane * 2);
    f2 go = { (agx + g * xr.x) * g, (agy + g * xr.y) * g };
    f2 so = { 0.5f * xr.x + 0.5f * asx, 0.5f * xr.y + 0.5f * asy };
    st2(g1 + r * DF + lane * 2, go);
    st2(fp1 + r * DF + lane * 2, so);
}

// Steps 2,3: GCN step on gsrc + SCT step on ssrc (different gathers, shared indices),
// emitting hs = |fpc - fpn|^m.
__global__ void __launch_bounds__(256) k_step23(const int* __restrict__ rp, const int* __restrict__ ci,
                                                const float* __restrict__ cwg, const float* __restrict__ cws,
                                                const float* __restrict__ gsrc, const float* __restrict__ ssrc,
                                                const float* __restrict__ dg,
                                                float* __restrict__ gdst, float* __restrict__ sdst,
                                                float* __restrict__ hs,
                                                const int* __restrict__ mom, int N) {
    int t = threadIdx.x;
    int lane = t & 63;
    int r = blockIdx.x * 4 + (t >> 6);
    if (r >= N) return;
    int s = rp[r], e = rp[r + 1];
    float agx = 0.f, agy = 0.f, asx = 0.f, asy = 0.f;
    for (int j = s; j < e; ++j) {
        int c = ci[j];
        float wg = cwg[j], ws = cws[j];
        f2 gv = ld2(gsrc + c * DF + lane * 2);
        f2 sv = ld2(ssrc + c * DF + lane * 2);
        agx = fmaf(wg, gv.x, agx); agy = fmaf(wg, gv.y, agy);
        asx = fmaf(ws, sv.x, asx); asy = fmaf(ws, sv.y, asy);
    }
    float g = dg[r];
    f2 gr = ld2(gsrc + r * DF + lane * 2);
    f2 go = { (agx + g * gr.x) * g, (agy + g * gr.y) * g };
    st2(gdst + r * DF + lane * 2, go);
    f2 pv = ld2(ssrc + r * DF + lane * 2);
    f2 nv = { 0.5f * pv.x + 0.5f * asx, 0.5f * pv.y + 0.5f * asy };
    st2(sdst + r * DF + lane * 2, nv);
    float ddx = fabsf(pv.x - nv.x), ddy = fabsf(pv.y - nv.y);
    int m = mom[0];
    f2 ho;
    if (m == 1) { ho.x = ddx; ho.y = ddy; }
    else        { ho.x = powf(ddx, (float)m); ho.y = powf(ddy, (float)m); }
    st2(hs + r * DF + lane * 2, ho);
}

// Step 4: SCT only; fp4 itself is dead — emit only hs.
__global__ void __launch_bounds__(256) k_step4(const int* __restrict__ rp, const int* __restrict__ ci,
                                               const float* __restrict__ cws,
                                               const float* __restrict__ ssrc,
                                               float* __restrict__ hs,
                                               const int* __restrict__ mom, int N) {
    int t = threadIdx.x;
    int lane = t & 63;
    int r = blockIdx.x * 4 + (t >> 6);
    if (r >= N) return;
    int s = rp[r], e = rp[r + 1];
    float asx = 0.f, asy = 0.f;
    for (int j = s; j < e; ++j) {
        float ws = cws[j];
        f2 sv = ld2(ssrc + ci[j] * DF + lane * 2);
        asx = fmaf(ws, sv.x, asx); asy = fmaf(ws, sv.y, asy);
    }
    f2 pv = ld2(ssrc + r * DF + lane * 2);
    float ddx = fabsf(pv.x - (0.5f * pv.x + 0.5f * asx));
    float ddy = fabsf(pv.y - (0.5f * pv.y + 0.5f * asy));
    int m = mom[0];
    f2 ho;
    if (m == 1) { ho.x = ddx; ho.y = ddy; }
    else        { ho.x = powf(ddx, (float)m); ho.y = powf(ddy, (float)m); }
    st2(hs + r * DF + lane * 2, ho);
}

__global__ void __launch_bounds__(128) k_attn(const float* __restrict__ X,
                                              const float* __restrict__ g1,
                                              const float* __restrict__ g2,
                                              const float* __restrict__ g3,
                                              const float* __restrict__ s1,
                                              const float* __restrict__ s2,
                                              const float* __restrict__ s3,
                                              const float* __restrict__ a,
                                              float* __restrict__ hp) {
    int n = blockIdx.x, d = threadIdx.x;
    int idx = n * DF + d;
    float hv[6];
    float gv1 = g1[idx], gv2 = g2[idx], gv3 = g3[idx];
    hv[0] = gv1 > 0.f ? gv1 : NEG * gv1;
    hv[1] = gv2 > 0.f ? gv2 : NEG * gv2;
    hv[2] = gv3 > 0.f ? gv3 : NEG * gv3;
    hv[3] = s1[idx]; hv[4] = s2[idx]; hv[5] = s3[idx];
    float xv = X[idx];
    float a1 = a[d], a2 = a[DF + d];
    float part[7];
    part[0] = fmaxf(xv, 0.f) * a1;
#pragma unroll
    for (int c = 0; c < 6; ++c) part[c + 1] = fmaxf(hv[c], 0.f) * a2;
#pragma unroll
    for (int k = 0; k < 7; ++k) {
        float v = part[k];
#pragma unroll
        for (int off = 32; off > 0; off >>= 1) v += __shfl_down(v, off, 64);
        part[k] = v;
    }
    __shared__ float sw[2][7];
    int wid = d >> 6, lane = d & 63;
    if (lane == 0) {
#pragma unroll
        for (int k = 0; k < 7; ++k) sw[wid][k] = part[k];
    }
    __syncthreads();
    float base = sw[0][0] + sw[1][0];
    float ev[6];
    float mx = -1e30f;
#pragma unroll
    for (int c = 0; c < 6; ++c) { ev[c] = base + sw[0][c + 1] + sw[1][c + 1]; mx = fmaxf(mx, ev[c]); }
    float ssum = 0.f;
#pragma unroll
    for (int c = 0; c < 6; ++c) { ev[c] = __expf(ev[c] - mx); ssum += ev[c]; }
    float inv = 1.f / ssum;
    float acc = 0.f;
#pragma unroll
    for (int c = 0; c < 6; ++c) acc += ev[c] * hv[c];
    hp[idx] = acc * inv * (1.0f / 6.0f);
}

__global__ void k_tw(const float* __restrict__ w, float* __restrict__ wt) {
    int i = blockIdx.x * blockDim.x + threadIdx.x;
    if (i < DF * DF) {
        int o = i >> 7, k = i & 127;
        wt[k * DF + o] = w[i];
    }
}

__global__ void __launch_bounds__(128) k_mlp1(const float* __restrict__ in, const float* __restrict__ wt,
                                              const float* __restrict__ bias,
                                              float* __restrict__ out) {
    int r = blockIdx.x, o = threadIdx.x;
    const float* inr = in + r * DF;
    float acc = bias[o];
#pragma unroll 8
    for (int k = 0; k < DF; ++k) acc = fmaf(inr[k], wt[k * DF + o], acc);
    out[r * DF + o] = acc > 0.f ? acc : NEG * acc;
}

__global__ void __launch_bounds__(128) k_mlp2(const float* __restrict__ in, const float* __restrict__ wt,
                                              const float* __restrict__ bias,
                                              float* __restrict__ out) {
    int r = blockIdx.x, o = threadIdx.x;
    const float* inr = in + r * DF;
    float acc = bias[o];
#pragma unroll 8
    for (int k = 0; k < DF; ++k) acc = fmaf(inr[k], wt[k * DF + o], acc);
    out[r * DF + o] = acc > 0.f ? acc : NEG * acc;
}

extern "C" void kernel_launch(void* const* d_in, const int* in_sizes, int n_in,
                              void* d_out, int out_size, void* d_ws, size_t ws_size,
                              hipStream_t stream) {
    const float* X  = (const float*)d_in[0];
    const int*   ei = (const int*)d_in[1];
    const float* ew = (const float*)d_in[2];
    const float* W1 = (const float*)d_in[3];
    const float* b1 = (const float*)d_in[4];
    const float* W2 = (const float*)d_in[5];
    const float* b2 = (const float*)d_in[6];
    const float* a  = (const float*)d_in[7];
    const int*  mom = (const int*)d_in[8];

    const int N = in_sizes[0] / DF;
    const int E = in_sizes[2];
    const int* row = ei;
    const int* col = ei + E;
    const size_t ND = (size_t)N * DF;

    char* p = (char*)d_ws;
    auto alloc = [&](size_t bytes) -> void* {
        char* r = p;
        p += (bytes + 255) & ~(size_t)255;
        return (void*)r;
    };
    float* G1 = (float*)alloc(ND * 4);
    float* G2 = (float*)alloc(ND * 4);
    float* G3 = (float*)alloc(ND * 4);
    float* S1 = (float*)alloc(ND * 4);
    float* S2 = (float*)alloc(ND * 4);
    float* S3 = (float*)alloc(ND * 4);
    float* P  = (float*)alloc(ND * 4);
    float* Q  = (float*)alloc(ND * 4);
    float* cdeg = (float*)alloc((size_t)N * 4);
    int*   rcnt = (int*)alloc((size_t)N * 4);
    float* dg   = (float*)alloc((size_t)N * 4);
    float* dinv = (float*)alloc((size_t)N * 4);
    int*   rp   = (int*)alloc((size_t)(N + 1) * 4);
    int*   cur  = (int*)alloc((size_t)N * 4);
    int*   bsum = (int*)alloc((size_t)256 * 4);
    int*   ci   = (int*)alloc((size_t)E * 4);
    float* cwg  = (float*)alloc((size_t)E * 4);
    float* cws  = (float*)alloc((size_t)E * 4);
    float* Wt1  = (float*)alloc((size_t)DF * DF * 4);
    float* Wt2  = (float*)alloc((size_t)DF * DF * 4);

    if ((size_t)(p - (char*)d_ws) > ws_size) {
        k_sentinel<<<(out_size + 255) / 256, 256, 0, stream>>>((float*)d_out, out_size);
        return;
    }

    hipMemsetAsync(cdeg, 0, (size_t)N * 4, stream);
    hipMemsetAsync(rcnt, 0, (size_t)N * 4, stream);

    int eb = (E + 255) / 256;
    k_deg<<<eb, 256, 0, stream>>>(row, col, ew, cdeg, rcnt, E);
    k_derive<<<(N + 255) / 256, 256, 0, stream>>>(cdeg, dg, dinv, N);

    int SB = (N + 1023) / 1024;   // scan blocks (1024 elems each)
    k_scan1<<<SB, 256, 0, stream>>>(rcnt, rp, bsum, N);
    k_scan2<<<1, 64, 0, stream>>>(bsum, SB);
    k_scan3<<<(N + 255) / 256, 256, 0, stream>>>(bsum, rp, cur, N, SB);

    k_scatter<<<eb, 256, 0, stream>>>(row, col, ew, dg, dinv, cur, ci, cwg, cws, E);

    int rb = (N + 3) / 4;  // 4 rows (waves) per 256-thread block
    // Step 1 (shared X gathers): G1, fp1->P
    k_step1<<<rb, 256, 0, stream>>>(rp, ci, cwg, cws, X, dg, G1, P, N);
    // Step 2: G1->G2, P->Q (fp2), S1
    k_step23<<<rb, 256, 0, stream>>>(rp, ci, cwg, cws, G1, P, dg, G2, Q, S1, mom, N);
    // Step 3: G2->G3, Q->P (fp3), S2
    k_step23<<<rb, 256, 0, stream>>>(rp, ci, cwg, cws, G2, Q, dg, G3, P, S2, mom, N);
    // Step 4: SCT only from P (fp3), S3
    k_step4<<<rb, 256, 0, stream>>>(rp, ci, cws, P, S3, mom, N);

    // Attention -> h_prime into Q
    k_attn<<<N, DF, 0, stream>>>(X, G1, G2, G3, S1, S2, S3, a, Q);

    // MLP
    k_tw<<<(DF * DF + 255) / 256, 256, 0, stream>>>(W1, Wt1);
    k_tw<<<(DF * DF + 255) / 256, 256, 0, stream>>>(W2, Wt2);
    k_mlp1<<<N, DF, 0, stream>>>(Q, Wt1, b1, P);
    k_mlp2<<<N, DF, 0, stream>>>(P, Wt2, b2, (float*)d_out);
}

// Round 4
// 839.809 us; speedup vs baseline: 1.5128x; 1.1158x over previous
//
#include <hip/hip_runtime.h>
#include <cstdint>
#include <cstddef>

#define DF 128
#define NEG 0.01f
typedef unsigned int u32;

struct f2 { float x, y; };
static __device__ __forceinline__ f2 ld2(const float* p) { return *(const f2*)p; }
static __device__ __forceinline__ void st2(float* p, f2 v) { *(f2*)p = v; }

// packed bf16 pair <-> floats (element 0 in low 16 bits), round-to-nearest-even
static __device__ __forceinline__ void ubf(u32 p, float& a, float& b) {
    a = __uint_as_float(p << 16);
    b = __uint_as_float(p & 0xffff0000u);
}
static __device__ __forceinline__ u32 pbf(float a, float b) {
    u32 ua = __float_as_uint(a), ub = __float_as_uint(b);
    ua += 0x7fffu + ((ua >> 16) & 1u);
    ub += 0x7fffu + ((ub >> 16) & 1u);
    return (ua >> 16) | (ub & 0xffff0000u);
}
static __device__ __forceinline__ int decode_m(int raw) {
    return (raw == 1 || raw == 16256 || raw == 1065353216) ? 1
         : (raw > 1 && raw < 16) ? raw : 1;
}

__global__ void k_sentinel(float* out, int n) {
    int i = blockIdx.x * blockDim.x + threadIdx.x;
    if (i < n) out[i] = 12345.0f;
}

__global__ void k_deg(const int* __restrict__ row, const int* __restrict__ col,
                      const float* __restrict__ w,
                      float* __restrict__ cdeg, int* __restrict__ rcnt, int E) {
    int e = blockIdx.x * blockDim.x + threadIdx.x;
    if (e < E) {
        atomicAdd(&cdeg[col[e]], w[e]);
        atomicAdd(&rcnt[row[e]], 1);
    }
}

__global__ void k_derive(const float* __restrict__ cdeg, float* __restrict__ dg,
                         float* __restrict__ dinv, int N) {
    int n = blockIdx.x * blockDim.x + threadIdx.x;
    if (n < N) {
        float c = cdeg[n];
        dg[n] = rsqrtf(c + 1.0f);
        dinv[n] = 1.0f / c;
    }
}

__global__ void k_xcast(const float* __restrict__ x, u32* __restrict__ xb, int n2) {
    int i = blockIdx.x * blockDim.x + threadIdx.x;
    if (i < n2) {
        f2 v = ld2(x + i * 2);
        xb[i] = pbf(v.x, v.y);
    }
}

// ---- device-wide exclusive scan over rcnt ----
__global__ void __launch_bounds__(256) k_scan1(const int* __restrict__ cnt,
                                               int* __restrict__ pre,
                                               int* __restrict__ bsum, int N) {
    int t = threadIdx.x;
    int base = blockIdx.x * 1024 + t * 4;
    int v0 = 0, v1 = 0, v2 = 0, v3 = 0;
    if (base + 3 < N) {
        int4 q = *(const int4*)(cnt + base);
        v0 = q.x; v1 = q.y; v2 = q.z; v3 = q.w;
    } else {
        if (base     < N) v0 = cnt[base];
        if (base + 1 < N) v1 = cnt[base + 1];
        if (base + 2 < N) v2 = cnt[base + 2];
        if (base + 3 < N) v3 = cnt[base + 3];
    }
    int tt = v0 + v1 + v2 + v3;
    __shared__ int s[256];
    s[t] = tt; __syncthreads();
    for (int off = 1; off < 256; off <<= 1) {
        int v = (t >= off) ? s[t - off] : 0;
        __syncthreads();
        s[t] += v;
        __syncthreads();
    }
    int ex = (t == 0) ? 0 : s[t - 1];
    if (base     < N) pre[base]     = ex;
    if (base + 1 < N) pre[base + 1] = ex + v0;
    if (base + 2 < N) pre[base + 2] = ex + v0 + v1;
    if (base + 3 < N) pre[base + 3] = ex + v0 + v1 + v2;
    if (t == 255) bsum[blockIdx.x] = s[255];
}

__global__ void k_scan2(int* __restrict__ bsum, int B) {
    if (threadIdx.x == 0 && blockIdx.x == 0) {
        int run = 0;
        for (int i = 0; i < B; ++i) { int v = bsum[i]; bsum[i] = run; run += v; }
        bsum[B] = run;
    }
}

__global__ void __launch_bounds__(256) k_scan3(const int* __restrict__ bsum,
                                               int* __restrict__ rp, int* __restrict__ cur,
                                               int N, int B) {
    int i = blockIdx.x * 256 + threadIdx.x;
    if (i < N) {
        int v = rp[i] + bsum[i >> 10];
        rp[i] = v;
        cur[i] = v;
    }
    if (i == 0) rp[N] = bsum[B];
}

__global__ void k_scatter(const int* __restrict__ row, const int* __restrict__ col,
                          const float* __restrict__ w,
                          const float* __restrict__ dg, const float* __restrict__ dinv,
                          int* __restrict__ cur, int* __restrict__ ci,
                          float* __restrict__ cwg, float* __restrict__ cws, int E) {
    int e = blockIdx.x * blockDim.x + threadIdx.x;
    if (e < E) {
        int r = row[e], c = col[e];
        float wf = w[e];
        int p = atomicAdd(&cur[r], 1);
        ci[p] = c;
        cwg[p] = wf * dg[c];
        cws[p] = wf * dinv[c];
    }
}

// ---- SPMM tower: one 64-lane wave per row, 2 features/lane, bf16 gathers ----
// Step 1: GCN1 + SCT1 share the X gathers. X local term in f32.
__global__ void __launch_bounds__(256) k_step1(const int* __restrict__ rp, const int* __restrict__ ci,
                                               const float* __restrict__ cwg, const float* __restrict__ cws,
                                               const float* __restrict__ X, const u32* __restrict__ Xb,
                                               const float* __restrict__ dg,
                                               u32* __restrict__ g1b,
                                               float* __restrict__ fp1, u32* __restrict__ fp1b, int N) {
    int t = threadIdx.x;
    int lane = t & 63;
    int r = blockIdx.x * 4 + (t >> 6);
    if (r >= N) return;
    int s = rp[r], e = rp[r + 1];
    float agx = 0.f, agy = 0.f, asx = 0.f, asy = 0.f;
    for (int j = s; j < e; ++j) {
        int c = ci[j];
        float wg = cwg[j], ws = cws[j];
        float vx, vy; ubf(Xb[c * 64 + lane], vx, vy);
        agx = fmaf(wg, vx, agx); agy = fmaf(wg, vy, agy);
        asx = fmaf(ws, vx, asx); asy = fmaf(ws, vy, asy);
    }
    float g = dg[r];
    f2 xr = ld2(X + r * DF + lane * 2);
    float gox = (agx + g * xr.x) * g, goy = (agy + g * xr.y) * g;
    g1b[r * 64 + lane] = pbf(gox, goy);
    float sox = 0.5f * xr.x + 0.5f * asx, soy = 0.5f * xr.y + 0.5f * asy;
    st2(fp1 + r * DF + lane * 2, {sox, soy});
    fp1b[r * 64 + lane] = pbf(sox, soy);
}

// Steps 2,3: GCN from gsb (bf16), SCT from ssb (bf16 gathers, f32 local state sfull).
__global__ void __launch_bounds__(256) k_step23(const int* __restrict__ rp, const int* __restrict__ ci,
                                                const float* __restrict__ cwg, const float* __restrict__ cws,
                                                const u32* __restrict__ gsb, const u32* __restrict__ ssb,
                                                const float* __restrict__ sfull,
                                                const float* __restrict__ dg,
                                                u32* __restrict__ gdb,
                                                float* __restrict__ sdst, u32* __restrict__ sdb,
                                                u32* __restrict__ hsb,
                                                const int* __restrict__ mom, int N) {
    int t = threadIdx.x;
    int lane = t & 63;
    int r = blockIdx.x * 4 + (t >> 6);
    if (r >= N) return;
    int s = rp[r], e = rp[r + 1];
    float agx = 0.f, agy = 0.f, asx = 0.f, asy = 0.f;
    for (int j = s; j < e; ++j) {
        int c = ci[j];
        float wg = cwg[j], ws = cws[j];
        float gx, gy, sx, sy;
        ubf(gsb[c * 64 + lane], gx, gy);
        ubf(ssb[c * 64 + lane], sx, sy);
        agx = fmaf(wg, gx, agx); agy = fmaf(wg, gy, agy);
        asx = fmaf(ws, sx, asx); asy = fmaf(ws, sy, asy);
    }
    float g = dg[r];
    float grx, gry; ubf(gsb[r * 64 + lane], grx, gry);
    float gox = (agx + g * grx) * g, goy = (agy + g * gry) * g;
    gdb[r * 64 + lane] = pbf(gox, goy);
    f2 pv = ld2(sfull + r * DF + lane * 2);
    float nvx = 0.5f * pv.x + 0.5f * asx, nvy = 0.5f * pv.y + 0.5f * asy;
    st2(sdst + r * DF + lane * 2, {nvx, nvy});
    sdb[r * 64 + lane] = pbf(nvx, nvy);
    float ddx = fabsf(pv.x - nvx), ddy = fabsf(pv.y - nvy);
    int m = decode_m(mom[0]);
    if (m != 1) { ddx = powf(ddx, (float)m); ddy = powf(ddy, (float)m); }
    hsb[r * 64 + lane] = pbf(ddx, ddy);
}

// Step 4: SCT only; fp4 dead — emit only hs.
__global__ void __launch_bounds__(256) k_step4(const int* __restrict__ rp, const int* __restrict__ ci,
                                               const float* __restrict__ cws,
                                               const u32* __restrict__ ssb,
                                               const float* __restrict__ sfull,
                                               u32* __restrict__ hsb,
                                               const int* __restrict__ mom, int N) {
    int t = threadIdx.x;
    int lane = t & 63;
    int r = blockIdx.x * 4 + (t >> 6);
    if (r >= N) return;
    int s = rp[r], e = rp[r + 1];
    float asx = 0.f, asy = 0.f;
    for (int j = s; j < e; ++j) {
        float ws = cws[j];
        float sx, sy; ubf(ssb[ci[j] * 64 + lane], sx, sy);
        asx = fmaf(ws, sx, asx); asy = fmaf(ws, sy, asy);
    }
    f2 pv = ld2(sfull + r * DF + lane * 2);
    float ddx = fabsf(pv.x - (0.5f * pv.x + 0.5f * asx));
    float ddy = fabsf(pv.y - (0.5f * pv.y + 0.5f * asy));
    int m = decode_m(mom[0]);
    if (m != 1) { ddx = powf(ddx, (float)m); ddy = powf(ddy, (float)m); }
    hsb[r * 64 + lane] = pbf(ddx, ddy);
}

// Attention: one wave per row, 2 features/lane, 64-lane butterfly reductions.
__global__ void __launch_bounds__(256) k_attn(const float* __restrict__ X,
                                              const u32* __restrict__ g1, const u32* __restrict__ g2,
                                              const u32* __restrict__ g3, const u32* __restrict__ s1,
                                              const u32* __restrict__ s2, const u32* __restrict__ s3,
                                              const float* __restrict__ a,
                                              float* __restrict__ hp, int N) {
    int t = threadIdx.x;
    int lane = t & 63;
    int r = blockIdx.x * 4 + (t >> 6);
    if (r >= N) return;
    int iw = r * 64 + lane;
    float hx[6], hy[6];
    ubf(g1[iw], hx[0], hy[0]);
    ubf(g2[iw], hx[1], hy[1]);
    ubf(g3[iw], hx[2], hy[2]);
    ubf(s1[iw], hx[3], hy[3]);
    ubf(s2[iw], hx[4], hy[4]);
    ubf(s3[iw], hx[5], hy[5]);
#pragma unroll
    for (int c = 0; c < 3; ++c) {
        hx[c] = hx[c] > 0.f ? hx[c] : NEG * hx[c];
        hy[c] = hy[c] > 0.f ? hy[c] : NEG * hy[c];
    }
    f2 xr = ld2(X + r * DF + lane * 2);
    f2 a1 = ld2(a + lane * 2);
    f2 a2 = ld2(a + DF + lane * 2);
    float part[7];
    part[0] = fmaxf(xr.x, 0.f) * a1.x + fmaxf(xr.y, 0.f) * a1.y;
#pragma unroll
    for (int c = 0; c < 6; ++c)
        part[c + 1] = fmaxf(hx[c], 0.f) * a2.x + fmaxf(hy[c], 0.f) * a2.y;
#pragma unroll
    for (int k = 0; k < 7; ++k) {
        float v = part[k];
#pragma unroll
        for (int m = 32; m > 0; m >>= 1) v += __shfl_xor(v, m, 64);
        part[k] = v;
    }
    float ev[6], mx = -1e30f;
#pragma unroll
    for (int c = 0; c < 6; ++c) { ev[c] = part[0] + part[c + 1]; mx = fmaxf(mx, ev[c]); }
    float ssum = 0.f;
#pragma unroll
    for (int c = 0; c < 6; ++c) { ev[c] = __expf(ev[c] - mx); ssum += ev[c]; }
    float sc = 1.f / (6.f * ssum);
    float ox = 0.f, oy = 0.f;
#pragma unroll
    for (int c = 0; c < 6; ++c) { ox = fmaf(ev[c], hx[c], ox); oy = fmaf(ev[c], hy[c], oy); }
    st2(hp + r * DF + lane * 2, {ox * sc, oy * sc});
}

__global__ void k_tw(const float* __restrict__ w, float* __restrict__ wt) {
    int i = blockIdx.x * blockDim.x + threadIdx.x;
    if (i < DF * DF) {
        int o = i >> 7, k = i & 127;
        wt[k * DF + o] = w[i];
    }
}

// MLP layer: weights staged in LDS once per block, grid-stride over row pairs.
__global__ void __launch_bounds__(256) k_mlp(const float* __restrict__ in,
                                             const float* __restrict__ Wt,
                                             const float* __restrict__ bias,
                                             float* __restrict__ out, int N) {
    __shared__ float wt[DF * DF];
    __shared__ float rows[2][DF];
    int t = threadIdx.x;
    for (int i = t; i < DF * DF / 4; i += 256)
        ((float4*)wt)[i] = ((const float4*)Wt)[i];
    int rg = t >> 7, o = t & 127;
    float b = bias[o];
    for (int r0 = blockIdx.x * 2; r0 < N; r0 += gridDim.x * 2) {
        int r = r0 + rg;
        __syncthreads();
        if (r < N) rows[rg][o] = in[r * DF + o];
        __syncthreads();
        if (r < N) {
            float acc = b;
#pragma unroll 8
            for (int k = 0; k < DF; ++k) acc = fmaf(rows[rg][k], wt[k * DF + o], acc);
            out[r * DF + o] = acc > 0.f ? acc : NEG * acc;
        }
    }
}

extern "C" void kernel_launch(void* const* d_in, const int* in_sizes, int n_in,
                              void* d_out, int out_size, void* d_ws, size_t ws_size,
                              hipStream_t stream) {
    const float* X  = (const float*)d_in[0];
    const int*   ei = (const int*)d_in[1];
    const float* ew = (const float*)d_in[2];
    const float* W1 = (const float*)d_in[3];
    const float* b1 = (const float*)d_in[4];
    const float* W2 = (const float*)d_in[5];
    const float* b2 = (const float*)d_in[6];
    const float* a  = (const float*)d_in[7];
    const int*  mom = (const int*)d_in[8];

    const int N = in_sizes[0] / DF;
    const int E = in_sizes[2];
    const int* row = ei;
    const int* col = ei + E;
    const size_t ND = (size_t)N * DF;
    const size_t ND2 = ND / 2;

    char* p = (char*)d_ws;
    auto alloc = [&](size_t bytes) -> void* {
        char* r = p;
        p += (bytes + 255) & ~(size_t)255;
        return (void*)r;
    };
    float* P  = (float*)alloc(ND * 4);   // fp state (f32)
    float* Q  = (float*)alloc(ND * 4);   // fp state (f32) / attn out / reuse
    u32* Xb  = (u32*)alloc(ND2 * 4);
    u32* G1b = (u32*)alloc(ND2 * 4);
    u32* G2b = (u32*)alloc(ND2 * 4);
    u32* G3b = (u32*)alloc(ND2 * 4);
    u32* Pb  = (u32*)alloc(ND2 * 4);
    u32* Qb  = (u32*)alloc(ND2 * 4);
    u32* S1b = (u32*)alloc(ND2 * 4);
    u32* S2b = (u32*)alloc(ND2 * 4);
    u32* S3b = (u32*)alloc(ND2 * 4);
    float* cdeg = (float*)alloc((size_t)N * 4);
    int*   rcnt = (int*)alloc((size_t)N * 4);
    float* dg   = (float*)alloc((size_t)N * 4);
    float* dinv = (float*)alloc((size_t)N * 4);
    int*   rp   = (int*)alloc((size_t)(N + 1) * 4);
    int*   cur  = (int*)alloc((size_t)N * 4);
    int*   bsum = (int*)alloc((size_t)256 * 4);
    int*   ci   = (int*)alloc((size_t)E * 4);
    float* cwg  = (float*)alloc((size_t)E * 4);
    float* cws  = (float*)alloc((size_t)E * 4);
    float* Wt1  = (float*)alloc((size_t)DF * DF * 4);
    float* Wt2  = (float*)alloc((size_t)DF * DF * 4);

    if ((size_t)(p - (char*)d_ws) > ws_size) {
        k_sentinel<<<(out_size + 255) / 256, 256, 0, stream>>>((float*)d_out, out_size);
        return;
    }

    hipMemsetAsync(cdeg, 0, (size_t)N * 4, stream);
    hipMemsetAsync(rcnt, 0, (size_t)N * 4, stream);

    int eb = (E + 255) / 256;
    k_deg<<<eb, 256, 0, stream>>>(row, col, ew, cdeg, rcnt, E);
    k_derive<<<(N + 255) / 256, 256, 0, stream>>>(cdeg, dg, dinv, N);
    k_xcast<<<(int)((ND2 + 255) / 256), 256, 0, stream>>>(X, Xb, (int)ND2);

    int SB = (N + 1023) / 1024;
    k_scan1<<<SB, 256, 0, stream>>>(rcnt, rp, bsum, N);
    k_scan2<<<1, 64, 0, stream>>>(bsum, SB);
    k_scan3<<<(N + 255) / 256, 256, 0, stream>>>(bsum, rp, cur, N, SB);

    k_scatter<<<eb, 256, 0, stream>>>(row, col, ew, dg, dinv, cur, ci, cwg, cws, E);

    int rb = (N + 3) / 4;
    // Step 1: X -> G1b, fp1(P,Pb)
    k_step1<<<rb, 256, 0, stream>>>(rp, ci, cwg, cws, X, Xb, dg, G1b, P, Pb, N);
    // Step 2: G1b -> G2b; fp1(P,Pb) -> fp2(Q,Qb); S1b
    k_step23<<<rb, 256, 0, stream>>>(rp, ci, cwg, cws, G1b, Pb, P, dg, G2b, Q, Qb, S1b, mom, N);
    // Step 3: G2b -> G3b; fp2(Q,Qb) -> fp3(P,Pb); S2b
    k_step23<<<rb, 256, 0, stream>>>(rp, ci, cwg, cws, G2b, Qb, Q, dg, G3b, P, Pb, S2b, mom, N);
    // Step 4: fp3(Pb,P) -> S3b
    k_step4<<<rb, 256, 0, stream>>>(rp, ci, cws, Pb, P, S3b, mom, N);

    // Attention -> h' into Q (f32)
    k_attn<<<rb, 256, 0, stream>>>(X, G1b, G2b, G3b, S1b, S2b, S3b, a, Q, N);

    // MLP with LDS-staged weights
    k_tw<<<(DF * DF + 255) / 256, 256, 0, stream>>>(W1, Wt1);
    k_tw<<<(DF * DF + 255) / 256, 256, 0, stream>>>(W2, Wt2);
    k_mlp<<<1024, 256, 0, stream>>>(Q, Wt1, b1, P, N);
    k_mlp<<<1024, 256, 0, stream>>>(P, Wt2, b2, (float*)d_out, N);
}

// Round 5
// 704.236 us; speedup vs baseline: 1.8041x; 1.1925x over previous
//
#include <hip/hip_runtime.h>
#include <cstdint>
#include <cstddef>

#define DF 128
#define NEG 0.01f
typedef unsigned int u32;

struct f2 { float x, y; };
static __device__ __forceinline__ f2 ld2(const float* p) { return *(const f2*)p; }
static __device__ __forceinline__ void st2(float* p, f2 v) { *(f2*)p = v; }

// packed bf16 pair <-> floats (element 0 in low 16 bits), round-to-nearest-even
static __device__ __forceinline__ void ubf(u32 p, float& a, float& b) {
    a = __uint_as_float(p << 16);
    b = __uint_as_float(p & 0xffff0000u);
}
static __device__ __forceinline__ u32 pbf(float a, float b) {
    u32 ua = __float_as_uint(a), ub = __float_as_uint(b);
    ua += 0x7fffu + ((ua >> 16) & 1u);
    ub += 0x7fffu + ((ub >> 16) & 1u);
    return (ua >> 16) | (ub & 0xffff0000u);
}
static __device__ __forceinline__ int decode_m(int raw) {
    return (raw == 1 || raw == 16256 || raw == 1065353216) ? 1
         : (raw > 1 && raw < 16) ? raw : 1;
}

__global__ void k_sentinel(float* out, int n) {
    int i = blockIdx.x * blockDim.x + threadIdx.x;
    if (i < n) out[i] = 12345.0f;
}

__global__ void k_deg(const int* __restrict__ row, const int* __restrict__ col,
                      const float* __restrict__ w,
                      float* __restrict__ cdeg, int* __restrict__ rcnt, int E) {
    int e = blockIdx.x * blockDim.x + threadIdx.x;
    if (e < E) {
        atomicAdd(&cdeg[col[e]], w[e]);
        atomicAdd(&rcnt[row[e]], 1);
    }
}

__global__ void k_derive(const float* __restrict__ cdeg, float* __restrict__ dg,
                         float* __restrict__ dinv, int N) {
    int n = blockIdx.x * blockDim.x + threadIdx.x;
    if (n < N) {
        float c = cdeg[n];
        dg[n] = rsqrtf(c + 1.0f);
        dinv[n] = 1.0f / c;
    }
}

__global__ void k_xcast(const float* __restrict__ x, u32* __restrict__ xb, int n2) {
    int i = blockIdx.x * blockDim.x + threadIdx.x;
    if (i < n2) {
        f2 v = ld2(x + i * 2);
        xb[i] = pbf(v.x, v.y);
    }
}

// ---- device-wide exclusive scan over rcnt ----
__global__ void __launch_bounds__(256) k_scan1(const int* __restrict__ cnt,
                                               int* __restrict__ pre,
                                               int* __restrict__ bsum, int N) {
    int t = threadIdx.x;
    int base = blockIdx.x * 1024 + t * 4;
    int v0 = 0, v1 = 0, v2 = 0, v3 = 0;
    if (base + 3 < N) {
        int4 q = *(const int4*)(cnt + base);
        v0 = q.x; v1 = q.y; v2 = q.z; v3 = q.w;
    } else {
        if (base     < N) v0 = cnt[base];
        if (base + 1 < N) v1 = cnt[base + 1];
        if (base + 2 < N) v2 = cnt[base + 2];
        if (base + 3 < N) v3 = cnt[base + 3];
    }
    int tt = v0 + v1 + v2 + v3;
    __shared__ int s[256];
    s[t] = tt; __syncthreads();
    for (int off = 1; off < 256; off <<= 1) {
        int v = (t >= off) ? s[t - off] : 0;
        __syncthreads();
        s[t] += v;
        __syncthreads();
    }
    int ex = (t == 0) ? 0 : s[t - 1];
    if (base     < N) pre[base]     = ex;
    if (base + 1 < N) pre[base + 1] = ex + v0;
    if (base + 2 < N) pre[base + 2] = ex + v0 + v1;
    if (base + 3 < N) pre[base + 3] = ex + v0 + v1 + v2;
    if (t == 255) bsum[blockIdx.x] = s[255];
}

__global__ void k_scan2(int* __restrict__ bsum, int B) {
    if (threadIdx.x == 0 && blockIdx.x == 0) {
        int run = 0;
        for (int i = 0; i < B; ++i) { int v = bsum[i]; bsum[i] = run; run += v; }
        bsum[B] = run;
    }
}

__global__ void __launch_bounds__(256) k_scan3(const int* __restrict__ bsum,
                                               int* __restrict__ rp, int* __restrict__ cur,
                                               int N, int B) {
    int i = blockIdx.x * 256 + threadIdx.x;
    if (i < N) {
        int v = rp[i] + bsum[i >> 10];
        rp[i] = v;
        cur[i] = v;
    }
    if (i == 0) rp[N] = bsum[B];
}

__global__ void k_scatter(const int* __restrict__ row, const int* __restrict__ col,
                          const float* __restrict__ w,
                          const float* __restrict__ dg, const float* __restrict__ dinv,
                          int* __restrict__ cur, int* __restrict__ ci,
                          float* __restrict__ cwg, float* __restrict__ cws, int E) {
    int e = blockIdx.x * blockDim.x + threadIdx.x;
    if (e < E) {
        int r = row[e], c = col[e];
        float wf = w[e];
        int p = atomicAdd(&cur[r], 1);
        ci[p] = c;
        cwg[p] = wf * dg[c];
        cws[p] = wf * dinv[c];
    }
}

// Interleaved mirror layout: row r occupies 128 u32 (512 B):
//   IL[r*128 + 2*k]   = bf16 pair of GCN channel, features (2k, 2k+1)
//   IL[r*128 + 2*k+1] = bf16 pair of fp (scattering) channel, features (2k, 2k+1)
// One wave (64 lanes) holds k = lane.

#define UN 8

// Step 1: GCN1 + SCT1 share the X gathers (bf16 mirror Xb, dword gathers).
__global__ void __launch_bounds__(256) k_step1(const int* __restrict__ rp, const int* __restrict__ ci,
                                               const float* __restrict__ cwg, const float* __restrict__ cws,
                                               const float* __restrict__ X, const u32* __restrict__ Xb,
                                               const float* __restrict__ dg,
                                               u32* __restrict__ il1, float* __restrict__ fp1, int N) {
    int t = threadIdx.x;
    int lane = t & 63;
    int r = blockIdx.x * 4 + (t >> 6);
    if (r >= N) return;
    int s = rp[r], e = rp[r + 1];
    float agx = 0.f, agy = 0.f, asx = 0.f, asy = 0.f;
    int j = s;
    for (; j + UN <= e; j += UN) {
        int c[UN];
#pragma unroll
        for (int u = 0; u < UN; ++u) c[u] = ci[j + u];
        u32 pv[UN];
#pragma unroll
        for (int u = 0; u < UN; ++u) pv[u] = Xb[c[u] * 64 + lane];
#pragma unroll
        for (int u = 0; u < UN; ++u) {
            float wg = cwg[j + u], ws = cws[j + u];
            float vx, vy; ubf(pv[u], vx, vy);
            agx = fmaf(wg, vx, agx); agy = fmaf(wg, vy, agy);
            asx = fmaf(ws, vx, asx); asy = fmaf(ws, vy, asy);
        }
    }
    for (; j < e; ++j) {
        int c = ci[j];
        float wg = cwg[j], ws = cws[j];
        float vx, vy; ubf(Xb[c * 64 + lane], vx, vy);
        agx = fmaf(wg, vx, agx); agy = fmaf(wg, vy, agy);
        asx = fmaf(ws, vx, asx); asy = fmaf(ws, vy, asy);
    }
    float g = dg[r];
    f2 xr = ld2(X + r * DF + lane * 2);
    float gox = (agx + g * xr.x) * g, goy = (agy + g * xr.y) * g;
    float sox = 0.5f * xr.x + 0.5f * asx, soy = 0.5f * xr.y + 0.5f * asy;
    uint2 o = { pbf(gox, goy), pbf(sox, soy) };
    *(uint2*)(il1 + r * 128 + 2 * lane) = o;
    st2(fp1 + r * DF + lane * 2, {sox, soy});
}

// Steps 2,3: one dwordx2 gather per edge serves BOTH towers.
__global__ void __launch_bounds__(256) k_step23(const int* __restrict__ rp, const int* __restrict__ ci,
                                                const float* __restrict__ cwg, const float* __restrict__ cws,
                                                const u32* __restrict__ ils,
                                                const float* __restrict__ sfull,
                                                const float* __restrict__ dg,
                                                u32* __restrict__ ild,
                                                float* __restrict__ sdst,
                                                u32* __restrict__ hsb,
                                                const int* __restrict__ mom, int N) {
    int t = threadIdx.x;
    int lane = t & 63;
    int r = blockIdx.x * 4 + (t >> 6);
    if (r >= N) return;
    int s = rp[r], e = rp[r + 1];
    float agx = 0.f, agy = 0.f, asx = 0.f, asy = 0.f;
    int j = s;
    for (; j + UN <= e; j += UN) {
        int c[UN];
#pragma unroll
        for (int u = 0; u < UN; ++u) c[u] = ci[j + u];
        uint2 pv[UN];
#pragma unroll
        for (int u = 0; u < UN; ++u) pv[u] = *(const uint2*)(ils + (size_t)c[u] * 128 + 2 * lane);
#pragma unroll
        for (int u = 0; u < UN; ++u) {
            float wg = cwg[j + u], ws = cws[j + u];
            float gx, gy, sx, sy;
            ubf(pv[u].x, gx, gy);
            ubf(pv[u].y, sx, sy);
            agx = fmaf(wg, gx, agx); agy = fmaf(wg, gy, agy);
            asx = fmaf(ws, sx, asx); asy = fmaf(ws, sy, asy);
        }
    }
    for (; j < e; ++j) {
        int c = ci[j];
        float wg = cwg[j], ws = cws[j];
        uint2 pv = *(const uint2*)(ils + (size_t)c * 128 + 2 * lane);
        float gx, gy, sx, sy;
        ubf(pv.x, gx, gy);
        ubf(pv.y, sx, sy);
        agx = fmaf(wg, gx, agx); agy = fmaf(wg, gy, agy);
        asx = fmaf(ws, sx, asx); asy = fmaf(ws, sy, asy);
    }
    float g = dg[r];
    float grx, gry; ubf(ils[r * 128 + 2 * lane], grx, gry);
    float gox = (agx + g * grx) * g, goy = (agy + g * gry) * g;
    f2 pvv = ld2(sfull + r * DF + lane * 2);
    float nvx = 0.5f * pvv.x + 0.5f * asx, nvy = 0.5f * pvv.y + 0.5f * asy;
    uint2 o = { pbf(gox, goy), pbf(nvx, nvy) };
    *(uint2*)(ild + r * 128 + 2 * lane) = o;
    st2(sdst + r * DF + lane * 2, {nvx, nvy});
    float ddx = fabsf(pvv.x - nvx), ddy = fabsf(pvv.y - nvy);
    int m = decode_m(mom[0]);
    if (m != 1) { ddx = powf(ddx, (float)m); ddy = powf(ddy, (float)m); }
    hsb[r * 64 + lane] = pbf(ddx, ddy);
}

// Step 4 + attention fused: SCT aggregation for S3, then per-row softmax over
// 6 channels, h' written directly. Everything is row-local to this wave.
__global__ void __launch_bounds__(256) k_step4attn(const int* __restrict__ rp, const int* __restrict__ ci,
                                                   const float* __restrict__ cws,
                                                   const u32* __restrict__ il1, const u32* __restrict__ il2,
                                                   const u32* __restrict__ il3,
                                                   const float* __restrict__ sfull,
                                                   const u32* __restrict__ s1b, const u32* __restrict__ s2b,
                                                   const float* __restrict__ X, const float* __restrict__ a,
                                                   float* __restrict__ hp,
                                                   const int* __restrict__ mom, int N) {
    int t = threadIdx.x;
    int lane = t & 63;
    int r = blockIdx.x * 4 + (t >> 6);
    if (r >= N) return;
    int s = rp[r], e = rp[r + 1];
    float asx = 0.f, asy = 0.f;
    int j = s;
    for (; j + UN <= e; j += UN) {
        int c[UN];
#pragma unroll
        for (int u = 0; u < UN; ++u) c[u] = ci[j + u];
        u32 pv[UN];
#pragma unroll
        for (int u = 0; u < UN; ++u) pv[u] = il3[(size_t)c[u] * 128 + 2 * lane + 1];
#pragma unroll
        for (int u = 0; u < UN; ++u) {
            float ws = cws[j + u];
            float sx, sy; ubf(pv[u], sx, sy);
            asx = fmaf(ws, sx, asx); asy = fmaf(ws, sy, asy);
        }
    }
    for (; j < e; ++j) {
        float ws = cws[j];
        float sx, sy; ubf(il3[(size_t)ci[j] * 128 + 2 * lane + 1], sx, sy);
        asx = fmaf(ws, sx, asx); asy = fmaf(ws, sy, asy);
    }
    f2 pvv = ld2(sfull + r * DF + lane * 2);
    float ddx = fabsf(pvv.x - (0.5f * pvv.x + 0.5f * asx));
    float ddy = fabsf(pvv.y - (0.5f * pvv.y + 0.5f * asy));
    int m = decode_m(mom[0]);
    if (m != 1) { ddx = powf(ddx, (float)m); ddy = powf(ddy, (float)m); }

    // --- attention (row-local) ---
    float hx[6], hy[6];
    ubf(il1[r * 128 + 2 * lane], hx[0], hy[0]);
    ubf(il2[r * 128 + 2 * lane], hx[1], hy[1]);
    ubf(il3[r * 128 + 2 * lane], hx[2], hy[2]);
    ubf(s1b[r * 64 + lane], hx[3], hy[3]);
    ubf(s2b[r * 64 + lane], hx[4], hy[4]);
    hx[5] = ddx; hy[5] = ddy;
#pragma unroll
    for (int c = 0; c < 3; ++c) {
        hx[c] = hx[c] > 0.f ? hx[c] : NEG * hx[c];
        hy[c] = hy[c] > 0.f ? hy[c] : NEG * hy[c];
    }
    f2 xr = ld2(X + r * DF + lane * 2);
    f2 a1 = ld2(a + lane * 2);
    f2 a2 = ld2(a + DF + lane * 2);
    float part[7];
    part[0] = fmaxf(xr.x, 0.f) * a1.x + fmaxf(xr.y, 0.f) * a1.y;
#pragma unroll
    for (int c = 0; c < 6; ++c)
        part[c + 1] = fmaxf(hx[c], 0.f) * a2.x + fmaxf(hy[c], 0.f) * a2.y;
#pragma unroll
    for (int k = 0; k < 7; ++k) {
        float v = part[k];
#pragma unroll
        for (int mm = 32; mm > 0; mm >>= 1) v += __shfl_xor(v, mm, 64);
        part[k] = v;
    }
    float ev[6], mx = -1e30f;
#pragma unroll
    for (int c = 0; c < 6; ++c) { ev[c] = part[0] + part[c + 1]; mx = fmaxf(mx, ev[c]); }
    float ssum = 0.f;
#pragma unroll
    for (int c = 0; c < 6; ++c) { ev[c] = __expf(ev[c] - mx); ssum += ev[c]; }
    float sc = 1.f / (6.f * ssum);
    float ox = 0.f, oy = 0.f;
#pragma unroll
    for (int c = 0; c < 6; ++c) { ox = fmaf(ev[c], hx[c], ox); oy = fmaf(ev[c], hy[c], oy); }
    st2(hp + r * DF + lane * 2, {ox * sc, oy * sc});
}

__global__ void k_tw(const float* __restrict__ w, float* __restrict__ wt) {
    int i = blockIdx.x * blockDim.x + threadIdx.x;
    if (i < DF * DF) {
        int o = i >> 7, k = i & 127;
        wt[k * DF + o] = w[i];
    }
}

// MLP layer: weights staged in LDS once per block, grid-stride over row pairs.
__global__ void __launch_bounds__(256) k_mlp(const float* __restrict__ in,
                                             const float* __restrict__ Wt,
                                             const float* __restrict__ bias,
                                             float* __restrict__ out, int N) {
    __shared__ float wt[DF * DF];
    __shared__ float rows[2][DF];
    int t = threadIdx.x;
    for (int i = t; i < DF * DF / 4; i += 256)
        ((float4*)wt)[i] = ((const float4*)Wt)[i];
    int rg = t >> 7, o = t & 127;
    float b = bias[o];
    for (int r0 = blockIdx.x * 2; r0 < N; r0 += gridDim.x * 2) {
        int r = r0 + rg;
        __syncthreads();
        if (r < N) rows[rg][o] = in[r * DF + o];
        __syncthreads();
        if (r < N) {
            float acc = b;
#pragma unroll 8
            for (int k = 0; k < DF; ++k) acc = fmaf(rows[rg][k], wt[k * DF + o], acc);
            out[r * DF + o] = acc > 0.f ? acc : NEG * acc;
        }
    }
}

extern "C" void kernel_launch(void* const* d_in, const int* in_sizes, int n_in,
                              void* d_out, int out_size, void* d_ws, size_t ws_size,
                              hipStream_t stream) {
    const float* X  = (const float*)d_in[0];
    const int*   ei = (const int*)d_in[1];
    const float* ew = (const float*)d_in[2];
    const float* W1 = (const float*)d_in[3];
    const float* b1 = (const float*)d_in[4];
    const float* W2 = (const float*)d_in[5];
    const float* b2 = (const float*)d_in[6];
    const float* a  = (const float*)d_in[7];
    const int*  mom = (const int*)d_in[8];

    const int N = in_sizes[0] / DF;
    const int E = in_sizes[2];
    const int* row = ei;
    const int* col = ei + E;
    const size_t ND = (size_t)N * DF;
    const size_t ND2 = ND / 2;

    char* p = (char*)d_ws;
    auto alloc = [&](size_t bytes) -> void* {
        char* r = p;
        p += (bytes + 255) & ~(size_t)255;
        return (void*)r;
    };
    float* P   = (float*)alloc(ND * 4);     // fp state (f32)
    float* Q   = (float*)alloc(ND * 4);     // fp state / attn out
    u32*   Xb  = (u32*)alloc(ND2 * 4);
    u32*   IL1 = (u32*)alloc(ND * 4);       // interleaved {G1, fp1} bf16 mirror
    u32*   IL2 = (u32*)alloc(ND * 4);
    u32*   IL3 = (u32*)alloc(ND * 4);
    u32*   S1b = (u32*)alloc(ND2 * 4);
    u32*   S2b = (u32*)alloc(ND2 * 4);
    float* cdeg = (float*)alloc((size_t)N * 4);
    int*   rcnt = (int*)alloc((size_t)N * 4);
    float* dg   = (float*)alloc((size_t)N * 4);
    float* dinv = (float*)alloc((size_t)N * 4);
    int*   rp   = (int*)alloc((size_t)(N + 1) * 4);
    int*   cur  = (int*)alloc((size_t)N * 4);
    int*   bsum = (int*)alloc((size_t)256 * 4);
    int*   ci   = (int*)alloc((size_t)E * 4);
    float* cwg  = (float*)alloc((size_t)E * 4);
    float* cws  = (float*)alloc((size_t)E * 4);
    float* Wt1  = (float*)alloc((size_t)DF * DF * 4);
    float* Wt2  = (float*)alloc((size_t)DF * DF * 4);

    if ((size_t)(p - (char*)d_ws) > ws_size) {
        k_sentinel<<<(out_size + 255) / 256, 256, 0, stream>>>((float*)d_out, out_size);
        return;
    }

    hipMemsetAsync(cdeg, 0, (size_t)N * 4, stream);
    hipMemsetAsync(rcnt, 0, (size_t)N * 4, stream);

    int eb = (E + 255) / 256;
    k_deg<<<eb, 256, 0, stream>>>(row, col, ew, cdeg, rcnt, E);
    k_derive<<<(N + 255) / 256, 256, 0, stream>>>(cdeg, dg, dinv, N);
    k_xcast<<<(int)((ND2 + 255) / 256), 256, 0, stream>>>(X, Xb, (int)ND2);

    int SB = (N + 1023) / 1024;
    k_scan1<<<SB, 256, 0, stream>>>(rcnt, rp, bsum, N);
    k_scan2<<<1, 64, 0, stream>>>(bsum, SB);
    k_scan3<<<(N + 255) / 256, 256, 0, stream>>>(bsum, rp, cur, N, SB);

    k_scatter<<<eb, 256, 0, stream>>>(row, col, ew, dg, dinv, cur, ci, cwg, cws, E);

    int rb = (N + 3) / 4;
    // Step 1: X -> IL1{G1,fp1}, fp1 f32 -> P
    k_step1<<<rb, 256, 0, stream>>>(rp, ci, cwg, cws, X, Xb, dg, IL1, P, N);
    // Step 2: IL1 -> IL2{G2,fp2}; P -> Q (fp2 f32); S1b
    k_step23<<<rb, 256, 0, stream>>>(rp, ci, cwg, cws, IL1, P, dg, IL2, Q, S1b, mom, N);
    // Step 3: IL2 -> IL3{G3,fp3}; Q -> P (fp3 f32); S2b
    k_step23<<<rb, 256, 0, stream>>>(rp, ci, cwg, cws, IL2, Q, dg, IL3, P, S2b, mom, N);
    // Step 4 + attention: S3 inline, h' -> Q
    k_step4attn<<<rb, 256, 0, stream>>>(rp, ci, cws, IL1, IL2, IL3, P, S1b, S2b, X, a, Q, mom, N);

    // MLP with LDS-staged weights
    k_tw<<<(DF * DF + 255) / 256, 256, 0, stream>>>(W1, Wt1);
    k_tw<<<(DF * DF + 255) / 256, 256, 0, stream>>>(W2, Wt2);
    k_mlp<<<1024, 256, 0, stream>>>(Q, Wt1, b1, P, N);
    k_mlp<<<1024, 256, 0, stream>>>(P, Wt2, b2, (float*)d_out, N);
}

// Round 6
// 533.666 us; speedup vs baseline: 2.3807x; 1.3196x over previous
//
#include <hip/hip_runtime.h>
#include <cstdint>
#include <cstddef>

#define DF 128
#define NEG 0.01f
typedef unsigned int u32;

struct f2 { float x, y; };
static __device__ __forceinline__ f2 ld2(const float* p) { return *(const f2*)p; }
static __device__ __forceinline__ void st2(float* p, f2 v) { *(f2*)p = v; }

// packed bf16 pair <-> floats (element 0 in low 16 bits), round-to-nearest-even
static __device__ __forceinline__ void ubf(u32 p, float& a, float& b) {
    a = __uint_as_float(p << 16);
    b = __uint_as_float(p & 0xffff0000u);
}
static __device__ __forceinline__ u32 pbf(float a, float b) {
    u32 ua = __float_as_uint(a), ub = __float_as_uint(b);
    ua += 0x7fffu + ((ua >> 16) & 1u);
    ub += 0x7fffu + ((ub >> 16) & 1u);
    return (ua >> 16) | (ub & 0xffff0000u);
}
static __device__ __forceinline__ unsigned short f2bf(float v) {
    u32 ua = __float_as_uint(v);
    ua += 0x7fffu + ((ua >> 16) & 1u);
    return (unsigned short)(ua >> 16);
}
static __device__ __forceinline__ int decode_m(int raw) {
    return (raw == 1 || raw == 16256 || raw == 1065353216) ? 1
         : (raw > 1 && raw < 16) ? raw : 1;
}

typedef __attribute__((ext_vector_type(8))) short s8v;   // 8 bf16 (4 VGPRs)
typedef __attribute__((ext_vector_type(4))) float f4v;   // MFMA accumulator

static __device__ __forceinline__ s8v pack8(const float* p) {
    union { u32 u[4]; s8v v; } r;
    r.u[0] = pbf(p[0], p[1]); r.u[1] = pbf(p[2], p[3]);
    r.u[2] = pbf(p[4], p[5]); r.u[3] = pbf(p[6], p[7]);
    return r.v;
}
static __device__ __forceinline__ s8v load8p(const u32* p) {
    union { uint4 u; s8v v; } r;
    r.u = *(const uint4*)p;
    return r.v;
}

__global__ void k_sentinel(float* out, int n) {
    int i = blockIdx.x * blockDim.x + threadIdx.x;
    if (i < n) out[i] = 12345.0f;
}

__global__ void k_deg(const int* __restrict__ row, const int* __restrict__ col,
                      const float* __restrict__ w,
                      float* __restrict__ cdeg, int* __restrict__ rcnt, int E) {
    int e = blockIdx.x * blockDim.x + threadIdx.x;
    if (e < E) {
        atomicAdd(&cdeg[col[e]], w[e]);
        atomicAdd(&rcnt[row[e]], 1);
    }
}

__global__ void k_derive(const float* __restrict__ cdeg, float* __restrict__ dg,
                         float* __restrict__ dinv, int N) {
    int n = blockIdx.x * blockDim.x + threadIdx.x;
    if (n < N) {
        float c = cdeg[n];
        dg[n] = rsqrtf(c + 1.0f);
        dinv[n] = 1.0f / c;
    }
}

__global__ void k_xcast(const float* __restrict__ x, u32* __restrict__ xb, int n2) {
    int i = blockIdx.x * blockDim.x + threadIdx.x;
    if (i < n2) {
        f2 v = ld2(x + i * 2);
        xb[i] = pbf(v.x, v.y);
    }
}

// ---- device-wide exclusive scan over rcnt ----
__global__ void __launch_bounds__(256) k_scan1(const int* __restrict__ cnt,
                                               int* __restrict__ pre,
                                               int* __restrict__ bsum, int N) {
    int t = threadIdx.x;
    int base = blockIdx.x * 1024 + t * 4;
    int v0 = 0, v1 = 0, v2 = 0, v3 = 0;
    if (base + 3 < N) {
        int4 q = *(const int4*)(cnt + base);
        v0 = q.x; v1 = q.y; v2 = q.z; v3 = q.w;
    } else {
        if (base     < N) v0 = cnt[base];
        if (base + 1 < N) v1 = cnt[base + 1];
        if (base + 2 < N) v2 = cnt[base + 2];
        if (base + 3 < N) v3 = cnt[base + 3];
    }
    int tt = v0 + v1 + v2 + v3;
    __shared__ int s[256];
    s[t] = tt; __syncthreads();
    for (int off = 1; off < 256; off <<= 1) {
        int v = (t >= off) ? s[t - off] : 0;
        __syncthreads();
        s[t] += v;
        __syncthreads();
    }
    int ex = (t == 0) ? 0 : s[t - 1];
    if (base     < N) pre[base]     = ex;
    if (base + 1 < N) pre[base + 1] = ex + v0;
    if (base + 2 < N) pre[base + 2] = ex + v0 + v1;
    if (base + 3 < N) pre[base + 3] = ex + v0 + v1 + v2;
    if (t == 255) bsum[blockIdx.x] = s[255];
}

__global__ void k_scan2(int* __restrict__ bsum, int B) {
    if (threadIdx.x == 0 && blockIdx.x == 0) {
        int run = 0;
        for (int i = 0; i < B; ++i) { int v = bsum[i]; bsum[i] = run; run += v; }
        bsum[B] = run;
    }
}

__global__ void __launch_bounds__(256) k_scan3(const int* __restrict__ bsum,
                                               int* __restrict__ rp, int* __restrict__ cur,
                                               int N, int B) {
    int i = blockIdx.x * 256 + threadIdx.x;
    if (i < N) {
        int v = rp[i] + bsum[i >> 10];
        rp[i] = v;
        cur[i] = v;
    }
    if (i == 0) rp[N] = bsum[B];
}

__global__ void k_scatter(const int* __restrict__ row, const int* __restrict__ col,
                          const float* __restrict__ w,
                          const float* __restrict__ dg, const float* __restrict__ dinv,
                          int* __restrict__ cur, int* __restrict__ ci,
                          float* __restrict__ cwg, float* __restrict__ cws, int E) {
    int e = blockIdx.x * blockDim.x + threadIdx.x;
    if (e < E) {
        int r = row[e], c = col[e];
        float wf = w[e];
        int p = atomicAdd(&cur[r], 1);
        ci[p] = c;
        cwg[p] = wf * dg[c];
        cws[p] = wf * dinv[c];
    }
}

// Interleaved mirror layout: row r occupies 128 u32 (512 B):
//   IL[r*128 + 2*k]   = bf16 pair of GCN channel, features (2k, 2k+1)
//   IL[r*128 + 2*k+1] = bf16 pair of fp (scattering) channel
#define UN 8

__global__ void __launch_bounds__(256) k_step1(const int* __restrict__ rp, const int* __restrict__ ci,
                                               const float* __restrict__ cwg, const float* __restrict__ cws,
                                               const float* __restrict__ X, const u32* __restrict__ Xb,
                                               const float* __restrict__ dg,
                                               u32* __restrict__ il1, float* __restrict__ fp1, int N) {
    int t = threadIdx.x;
    int lane = t & 63;
    int r = blockIdx.x * 4 + (t >> 6);
    if (r >= N) return;
    int s = rp[r], e = rp[r + 1];
    float agx = 0.f, agy = 0.f, asx = 0.f, asy = 0.f;
    int j = s;
    for (; j + UN <= e; j += UN) {
        int c[UN];
#pragma unroll
        for (int u = 0; u < UN; ++u) c[u] = ci[j + u];
        u32 pv[UN];
#pragma unroll
        for (int u = 0; u < UN; ++u) pv[u] = Xb[c[u] * 64 + lane];
#pragma unroll
        for (int u = 0; u < UN; ++u) {
            float wg = cwg[j + u], ws = cws[j + u];
            float vx, vy; ubf(pv[u], vx, vy);
            agx = fmaf(wg, vx, agx); agy = fmaf(wg, vy, agy);
            asx = fmaf(ws, vx, asx); asy = fmaf(ws, vy, asy);
        }
    }
    for (; j < e; ++j) {
        int c = ci[j];
        float wg = cwg[j], ws = cws[j];
        float vx, vy; ubf(Xb[c * 64 + lane], vx, vy);
        agx = fmaf(wg, vx, agx); agy = fmaf(wg, vy, agy);
        asx = fmaf(ws, vx, asx); asy = fmaf(ws, vy, asy);
    }
    float g = dg[r];
    f2 xr = ld2(X + r * DF + lane * 2);
    float gox = (agx + g * xr.x) * g, goy = (agy + g * xr.y) * g;
    float sox = 0.5f * xr.x + 0.5f * asx, soy = 0.5f * xr.y + 0.5f * asy;
    uint2 o = { pbf(gox, goy), pbf(sox, soy) };
    *(uint2*)(il1 + r * 128 + 2 * lane) = o;
    st2(fp1 + r * DF + lane * 2, {sox, soy});
}

__global__ void __launch_bounds__(256) k_step23(const int* __restrict__ rp, const int* __restrict__ ci,
                                                const float* __restrict__ cwg, const float* __restrict__ cws,
                                                const u32* __restrict__ ils,
                                                const float* __restrict__ sfull,
                                                const float* __restrict__ dg,
                                                u32* __restrict__ ild,
                                                float* __restrict__ sdst,
                                                u32* __restrict__ hsb,
                                                const int* __restrict__ mom, int N) {
    int t = threadIdx.x;
    int lane = t & 63;
    int r = blockIdx.x * 4 + (t >> 6);
    if (r >= N) return;
    int s = rp[r], e = rp[r + 1];
    float agx = 0.f, agy = 0.f, asx = 0.f, asy = 0.f;
    int j = s;
    for (; j + UN <= e; j += UN) {
        int c[UN];
#pragma unroll
        for (int u = 0; u < UN; ++u) c[u] = ci[j + u];
        uint2 pv[UN];
#pragma unroll
        for (int u = 0; u < UN; ++u) pv[u] = *(const uint2*)(ils + (size_t)c[u] * 128 + 2 * lane);
#pragma unroll
        for (int u = 0; u < UN; ++u) {
            float wg = cwg[j + u], ws = cws[j + u];
            float gx, gy, sx, sy;
            ubf(pv[u].x, gx, gy);
            ubf(pv[u].y, sx, sy);
            agx = fmaf(wg, gx, agx); agy = fmaf(wg, gy, agy);
            asx = fmaf(ws, sx, asx); asy = fmaf(ws, sy, asy);
        }
    }
    for (; j < e; ++j) {
        int c = ci[j];
        float wg = cwg[j], ws = cws[j];
        uint2 pv = *(const uint2*)(ils + (size_t)c * 128 + 2 * lane);
        float gx, gy, sx, sy;
        ubf(pv.x, gx, gy);
        ubf(pv.y, sx, sy);
        agx = fmaf(wg, gx, agx); agy = fmaf(wg, gy, agy);
        asx = fmaf(ws, sx, asx); asy = fmaf(ws, sy, asy);
    }
    float g = dg[r];
    float grx, gry; ubf(ils[r * 128 + 2 * lane], grx, gry);
    float gox = (agx + g * grx) * g, goy = (agy + g * gry) * g;
    f2 pvv = ld2(sfull + r * DF + lane * 2);
    float nvx = 0.5f * pvv.x + 0.5f * asx, nvy = 0.5f * pvv.y + 0.5f * asy;
    uint2 o = { pbf(gox, goy), pbf(nvx, nvy) };
    *(uint2*)(ild + r * 128 + 2 * lane) = o;
    st2(sdst + r * DF + lane * 2, {nvx, nvy});
    float ddx = fabsf(pvv.x - nvx), ddy = fabsf(pvv.y - nvy);
    int m = decode_m(mom[0]);
    if (m != 1) { ddx = powf(ddx, (float)m); ddy = powf(ddy, (float)m); }
    hsb[r * 64 + lane] = pbf(ddx, ddy);
}

// Step 4 + attention fused; h' emitted as PACKED BF16 (feeds MFMA MLP directly).
__global__ void __launch_bounds__(256) k_step4attn(const int* __restrict__ rp, const int* __restrict__ ci,
                                                   const float* __restrict__ cws,
                                                   const u32* __restrict__ il1, const u32* __restrict__ il2,
                                                   const u32* __restrict__ il3,
                                                   const float* __restrict__ sfull,
                                                   const u32* __restrict__ s1b, const u32* __restrict__ s2b,
                                                   const float* __restrict__ X, const float* __restrict__ a,
                                                   u32* __restrict__ hpb,
                                                   const int* __restrict__ mom, int N) {
    int t = threadIdx.x;
    int lane = t & 63;
    int r = blockIdx.x * 4 + (t >> 6);
    if (r >= N) return;
    int s = rp[r], e = rp[r + 1];
    float asx = 0.f, asy = 0.f;
    int j = s;
    for (; j + UN <= e; j += UN) {
        int c[UN];
#pragma unroll
        for (int u = 0; u < UN; ++u) c[u] = ci[j + u];
        u32 pv[UN];
#pragma unroll
        for (int u = 0; u < UN; ++u) pv[u] = il3[(size_t)c[u] * 128 + 2 * lane + 1];
#pragma unroll
        for (int u = 0; u < UN; ++u) {
            float ws = cws[j + u];
            float sx, sy; ubf(pv[u], sx, sy);
            asx = fmaf(ws, sx, asx); asy = fmaf(ws, sy, asy);
        }
    }
    for (; j < e; ++j) {
        float ws = cws[j];
        float sx, sy; ubf(il3[(size_t)ci[j] * 128 + 2 * lane + 1], sx, sy);
        asx = fmaf(ws, sx, asx); asy = fmaf(ws, sy, asy);
    }
    f2 pvv = ld2(sfull + r * DF + lane * 2);
    float ddx = fabsf(pvv.x - (0.5f * pvv.x + 0.5f * asx));
    float ddy = fabsf(pvv.y - (0.5f * pvv.y + 0.5f * asy));
    int m = decode_m(mom[0]);
    if (m != 1) { ddx = powf(ddx, (float)m); ddy = powf(ddy, (float)m); }

    float hx[6], hy[6];
    ubf(il1[r * 128 + 2 * lane], hx[0], hy[0]);
    ubf(il2[r * 128 + 2 * lane], hx[1], hy[1]);
    ubf(il3[r * 128 + 2 * lane], hx[2], hy[2]);
    ubf(s1b[r * 64 + lane], hx[3], hy[3]);
    ubf(s2b[r * 64 + lane], hx[4], hy[4]);
    hx[5] = ddx; hy[5] = ddy;
#pragma unroll
    for (int c = 0; c < 3; ++c) {
        hx[c] = hx[c] > 0.f ? hx[c] : NEG * hx[c];
        hy[c] = hy[c] > 0.f ? hy[c] : NEG * hy[c];
    }
    f2 xr = ld2(X + r * DF + lane * 2);
    f2 a1 = ld2(a + lane * 2);
    f2 a2 = ld2(a + DF + lane * 2);
    float part[7];
    part[0] = fmaxf(xr.x, 0.f) * a1.x + fmaxf(xr.y, 0.f) * a1.y;
#pragma unroll
    for (int c = 0; c < 6; ++c)
        part[c + 1] = fmaxf(hx[c], 0.f) * a2.x + fmaxf(hy[c], 0.f) * a2.y;
#pragma unroll
    for (int k = 0; k < 7; ++k) {
        float v = part[k];
#pragma unroll
        for (int mm = 32; mm > 0; mm >>= 1) v += __shfl_xor(v, mm, 64);
        part[k] = v;
    }
    float ev[6], mx = -1e30f;
#pragma unroll
    for (int c = 0; c < 6; ++c) { ev[c] = part[0] + part[c + 1]; mx = fmaxf(mx, ev[c]); }
    float ssum = 0.f;
#pragma unroll
    for (int c = 0; c < 6; ++c) { ev[c] = __expf(ev[c] - mx); ssum += ev[c]; }
    float sc = 1.f / (6.f * ssum);
    float ox = 0.f, oy = 0.f;
#pragma unroll
    for (int c = 0; c < 6; ++c) { ox = fmaf(ev[c], hx[c], ox); oy = fmaf(ev[c], hy[c], oy); }
    hpb[r * 64 + lane] = pbf(ox * sc, oy * sc);
}

// Fused 2-layer MLP via bf16 MFMA (16x16x32). 4 waves/block; wave w owns
// column-tiles {w, w+4} of W1 AND W2 as persistent register B-fragments.
// Layouts (HW-verified, m89/m91/m120): A[m=lane&15][k=(lane>>4)*8+j],
// B[k=(lane>>4)*8+j][n=lane&15], C/D: col=lane&15, row=(lane>>4)*4+reg.
__global__ void __launch_bounds__(256) k_mlp2x(const u32* __restrict__ hpb,
                                               const float* __restrict__ W1, const float* __restrict__ b1,
                                               const float* __restrict__ W2, const float* __restrict__ b2,
                                               float* __restrict__ out, int N, int NT) {
    __shared__ unsigned short ylds[16][136];  // +8 pad: 2-way-max bank aliasing
    int t = threadIdx.x, lane = t & 63, wv = t >> 6;
    int n15 = lane & 15, quad = lane >> 4;
    s8v w1f[2][4], w2f[2][4];
    float bias1[2], bias2[2];
#pragma unroll
    for (int i = 0; i < 2; ++i) {
        int ct = wv + 4 * i;
        int rw = ct * 16 + n15;           // weight row = output column
#pragma unroll
        for (int q = 0; q < 4; ++q) {
            w1f[i][q] = pack8(W1 + rw * DF + q * 32 + quad * 8);
            w2f[i][q] = pack8(W2 + rw * DF + q * 32 + quad * 8);
        }
        bias1[i] = b1[rw];
        bias2[i] = b2[rw];
    }
    for (int tile = blockIdx.x; tile < NT; tile += gridDim.x) {
        int row0 = tile * 16;
        int rA = row0 + n15; if (rA >= N) rA = N - 1;
        s8v a1[4];
        const u32* src = hpb + (size_t)rA * 64;
#pragma unroll
        for (int q = 0; q < 4; ++q) a1[q] = load8p(src + q * 16 + quad * 4);
        f4v acc0 = {0.f, 0.f, 0.f, 0.f}, acc1 = {0.f, 0.f, 0.f, 0.f};
#pragma unroll
        for (int q = 0; q < 4; ++q) {
            acc0 = __builtin_amdgcn_mfma_f32_16x16x32_bf16(a1[q], w1f[0][q], acc0, 0, 0, 0);
            acc1 = __builtin_amdgcn_mfma_f32_16x16x32_bf16(a1[q], w1f[1][q], acc1, 0, 0, 0);
        }
        __syncthreads();   // protect previous iteration's ylds reads
#pragma unroll
        for (int i = 0; i < 2; ++i) {
            int cb = (wv + 4 * i) * 16 + n15;
#pragma unroll
            for (int reg = 0; reg < 4; ++reg) {
                float v = (i == 0 ? acc0[reg] : acc1[reg]) + bias1[i];
                v = v > 0.f ? v : NEG * v;
                ylds[quad * 4 + reg][cb] = f2bf(v);
            }
        }
        __syncthreads();
        s8v a2[4];
#pragma unroll
        for (int q = 0; q < 4; ++q)
            a2[q] = *(const s8v*)&ylds[n15][q * 32 + quad * 8];
        f4v o0 = {0.f, 0.f, 0.f, 0.f}, o1 = {0.f, 0.f, 0.f, 0.f};
#pragma unroll
        for (int q = 0; q < 4; ++q) {
            o0 = __builtin_amdgcn_mfma_f32_16x16x32_bf16(a2[q], w2f[0][q], o0, 0, 0, 0);
            o1 = __builtin_amdgcn_mfma_f32_16x16x32_bf16(a2[q], w2f[1][q], o1, 0, 0, 0);
        }
#pragma unroll
        for (int i = 0; i < 2; ++i) {
            int cb = (wv + 4 * i) * 16 + n15;
#pragma unroll
            for (int reg = 0; reg < 4; ++reg) {
                int rr = row0 + quad * 4 + reg;
                if (rr < N) {
                    float v = (i == 0 ? o0[reg] : o1[reg]) + bias2[i];
                    out[(size_t)rr * DF + cb] = v > 0.f ? v : NEG * v;
                }
            }
        }
    }
}

extern "C" void kernel_launch(void* const* d_in, const int* in_sizes, int n_in,
                              void* d_out, int out_size, void* d_ws, size_t ws_size,
                              hipStream_t stream) {
    const float* X  = (const float*)d_in[0];
    const int*   ei = (const int*)d_in[1];
    const float* ew = (const float*)d_in[2];
    const float* W1 = (const float*)d_in[3];
    const float* b1 = (const float*)d_in[4];
    const float* W2 = (const float*)d_in[5];
    const float* b2 = (const float*)d_in[6];
    const float* a  = (const float*)d_in[7];
    const int*  mom = (const int*)d_in[8];

    const int N = in_sizes[0] / DF;
    const int E = in_sizes[2];
    const int* row = ei;
    const int* col = ei + E;
    const size_t ND = (size_t)N * DF;
    const size_t ND2 = ND / 2;

    char* p = (char*)d_ws;
    auto alloc = [&](size_t bytes) -> void* {
        char* r = p;
        p += (bytes + 255) & ~(size_t)255;
        return (void*)r;
    };
    float* P   = (float*)alloc(ND * 4);     // fp state (f32)
    float* Q   = (float*)alloc(ND * 4);     // fp state (f32)
    u32*   Xb  = (u32*)alloc(ND2 * 4);
    u32*   IL1 = (u32*)alloc(ND * 4);       // interleaved {G, fp} bf16 mirrors
    u32*   IL2 = (u32*)alloc(ND * 4);
    u32*   IL3 = (u32*)alloc(ND * 4);
    u32*   S1b = (u32*)alloc(ND2 * 4);
    u32*   S2b = (u32*)alloc(ND2 * 4);
    u32*   Qb  = (u32*)alloc(ND2 * 4);      // h' packed bf16
    float* cdeg = (float*)alloc((size_t)N * 4);
    int*   rcnt = (int*)alloc((size_t)N * 4);
    float* dg   = (float*)alloc((size_t)N * 4);
    float* dinv = (float*)alloc((size_t)N * 4);
    int*   rp   = (int*)alloc((size_t)(N + 1) * 4);
    int*   cur  = (int*)alloc((size_t)N * 4);
    int*   bsum = (int*)alloc((size_t)256 * 4);
    int*   ci   = (int*)alloc((size_t)E * 4);
    float* cwg  = (float*)alloc((size_t)E * 4);
    float* cws  = (float*)alloc((size_t)E * 4);

    if ((size_t)(p - (char*)d_ws) > ws_size) {
        k_sentinel<<<(out_size + 255) / 256, 256, 0, stream>>>((float*)d_out, out_size);
        return;
    }

    hipMemsetAsync(cdeg, 0, (size_t)N * 4, stream);
    hipMemsetAsync(rcnt, 0, (size_t)N * 4, stream);

    int eb = (E + 255) / 256;
    k_deg<<<eb, 256, 0, stream>>>(row, col, ew, cdeg, rcnt, E);
    k_derive<<<(N + 255) / 256, 256, 0, stream>>>(cdeg, dg, dinv, N);
    k_xcast<<<(int)((ND2 + 255) / 256), 256, 0, stream>>>(X, Xb, (int)ND2);

    int SB = (N + 1023) / 1024;
    k_scan1<<<SB, 256, 0, stream>>>(rcnt, rp, bsum, N);
    k_scan2<<<1, 64, 0, stream>>>(bsum, SB);
    k_scan3<<<(N + 255) / 256, 256, 0, stream>>>(bsum, rp, cur, N, SB);

    k_scatter<<<eb, 256, 0, stream>>>(row, col, ew, dg, dinv, cur, ci, cwg, cws, E);

    int rb = (N + 3) / 4;
    k_step1<<<rb, 256, 0, stream>>>(rp, ci, cwg, cws, X, Xb, dg, IL1, P, N);
    k_step23<<<rb, 256, 0, stream>>>(rp, ci, cwg, cws, IL1, P, dg, IL2, Q, S1b, mom, N);
    k_step23<<<rb, 256, 0, stream>>>(rp, ci, cwg, cws, IL2, Q, dg, IL3, P, S2b, mom, N);
    k_step4attn<<<rb, 256, 0, stream>>>(rp, ci, cws, IL1, IL2, IL3, P, S1b, S2b, X, a, Qb, mom, N);

    // Fused MFMA MLP: Qb -> d_out
    int NT = (N + 15) / 16;
    int gb = NT < 1024 ? NT : 1024;
    k_mlp2x<<<gb, 256, 0, stream>>>(Qb, W1, b1, W2, b2, (float*)d_out, N, NT);
}

// Round 7
// 499.683 us; speedup vs baseline: 2.5426x; 1.0680x over previous
//
#include <hip/hip_runtime.h>
#include <cstdint>
#include <cstddef>

#define DF 128
#define NEG 0.01f
typedef unsigned int u32;

struct f2 { float x, y; };
static __device__ __forceinline__ f2 ld2(const float* p) { return *(const f2*)p; }
static __device__ __forceinline__ void st2(float* p, f2 v) { *(f2*)p = v; }

// packed bf16 pair <-> floats (element 0 in low 16 bits), round-to-nearest-even
static __device__ __forceinline__ void ubf(u32 p, float& a, float& b) {
    a = __uint_as_float(p << 16);
    b = __uint_as_float(p & 0xffff0000u);
}
static __device__ __forceinline__ u32 pbf(float a, float b) {
    u32 ua = __float_as_uint(a), ub = __float_as_uint(b);
    ua += 0x7fffu + ((ua >> 16) & 1u);
    ub += 0x7fffu + ((ub >> 16) & 1u);
    return (ua >> 16) | (ub & 0xffff0000u);
}
static __device__ __forceinline__ unsigned short f2bf(float v) {
    u32 ua = __float_as_uint(v);
    ua += 0x7fffu + ((ua >> 16) & 1u);
    return (unsigned short)(ua >> 16);
}
static __device__ __forceinline__ int decode_m(int raw) {
    return (raw == 1 || raw == 16256 || raw == 1065353216) ? 1
         : (raw > 1 && raw < 16) ? raw : 1;
}

typedef __attribute__((ext_vector_type(8))) short s8v;   // 8 bf16 (4 VGPRs)
typedef __attribute__((ext_vector_type(4))) float f4v;   // MFMA accumulator

static __device__ __forceinline__ s8v pack8(const float* p) {
    union { u32 u[4]; s8v v; } r;
    r.u[0] = pbf(p[0], p[1]); r.u[1] = pbf(p[2], p[3]);
    r.u[2] = pbf(p[4], p[5]); r.u[3] = pbf(p[6], p[7]);
    return r.v;
}
static __device__ __forceinline__ s8v load8p(const u32* p) {
    union { uint4 u; s8v v; } r;
    r.u = *(const uint4*)p;
    return r.v;
}

__global__ void k_sentinel(float* out, int n) {
    int i = blockIdx.x * blockDim.x + threadIdx.x;
    if (i < n) out[i] = 12345.0f;
}

__global__ void k_deg(const int* __restrict__ row, const int* __restrict__ col,
                      const float* __restrict__ w,
                      float* __restrict__ cdeg, int* __restrict__ rcnt, int E) {
    int e = blockIdx.x * blockDim.x + threadIdx.x;
    if (e < E) {
        atomicAdd(&cdeg[col[e]], w[e]);
        atomicAdd(&rcnt[row[e]], 1);
    }
}

__global__ void k_derive(const float* __restrict__ cdeg, float* __restrict__ dg,
                         float* __restrict__ dinv, int N) {
    int n = blockIdx.x * blockDim.x + threadIdx.x;
    if (n < N) {
        float c = cdeg[n];
        dg[n] = rsqrtf(c + 1.0f);
        dinv[n] = 1.0f / c;
    }
}

__global__ void k_xcast(const float* __restrict__ x, u32* __restrict__ xb, int n2) {
    int i = blockIdx.x * blockDim.x + threadIdx.x;
    if (i < n2) {
        f2 v = ld2(x + i * 2);
        xb[i] = pbf(v.x, v.y);
    }
}

// ---- device-wide exclusive scan over rcnt ----
__global__ void __launch_bounds__(256) k_scan1(const int* __restrict__ cnt,
                                               int* __restrict__ pre,
                                               int* __restrict__ bsum, int N) {
    int t = threadIdx.x;
    int base = blockIdx.x * 1024 + t * 4;
    int v0 = 0, v1 = 0, v2 = 0, v3 = 0;
    if (base + 3 < N) {
        int4 q = *(const int4*)(cnt + base);
        v0 = q.x; v1 = q.y; v2 = q.z; v3 = q.w;
    } else {
        if (base     < N) v0 = cnt[base];
        if (base + 1 < N) v1 = cnt[base + 1];
        if (base + 2 < N) v2 = cnt[base + 2];
        if (base + 3 < N) v3 = cnt[base + 3];
    }
    int tt = v0 + v1 + v2 + v3;
    __shared__ int s[256];
    s[t] = tt; __syncthreads();
    for (int off = 1; off < 256; off <<= 1) {
        int v = (t >= off) ? s[t - off] : 0;
        __syncthreads();
        s[t] += v;
        __syncthreads();
    }
    int ex = (t == 0) ? 0 : s[t - 1];
    if (base     < N) pre[base]     = ex;
    if (base + 1 < N) pre[base + 1] = ex + v0;
    if (base + 2 < N) pre[base + 2] = ex + v0 + v1;
    if (base + 3 < N) pre[base + 3] = ex + v0 + v1 + v2;
    if (t == 255) bsum[blockIdx.x] = s[255];
}

__global__ void k_scan2(int* __restrict__ bsum, int B) {
    if (threadIdx.x == 0 && blockIdx.x == 0) {
        int run = 0;
        for (int i = 0; i < B; ++i) { int v = bsum[i]; bsum[i] = run; run += v; }
        bsum[B] = run;
    }
}

__global__ void __launch_bounds__(256) k_scan3(const int* __restrict__ bsum,
                                               int* __restrict__ rp, int* __restrict__ cur,
                                               int N, int B) {
    int i = blockIdx.x * 256 + threadIdx.x;
    if (i < N) {
        int v = rp[i] + bsum[i >> 10];
        rp[i] = v;
        cur[i] = v;
    }
    if (i == 0) rp[N] = bsum[B];
}

__global__ void k_scatter(const int* __restrict__ row, const int* __restrict__ col,
                          const float* __restrict__ w,
                          const float* __restrict__ dg, const float* __restrict__ dinv,
                          int* __restrict__ cur, int* __restrict__ ci,
                          float* __restrict__ cwg, float* __restrict__ cws, int E) {
    int e = blockIdx.x * blockDim.x + threadIdx.x;
    if (e < E) {
        int r = row[e], c = col[e];
        float wf = w[e];
        int p = atomicAdd(&cur[r], 1);
        ci[p] = c;
        cwg[p] = wf * dg[c];
        cws[p] = wf * dinv[c];
    }
}

// Interleaved mirror layout: row r occupies 128 u32 (512 B):
//   IL[r*128 + 2*k]   = bf16 pair of GCN channel, features (2k, 2k+1)
//   IL[r*128 + 2*k+1] = bf16 pair of fp (scattering) channel
#define UN 8

__global__ void __launch_bounds__(256) k_step1(const int* __restrict__ rp, const int* __restrict__ ci,
                                               const float* __restrict__ cwg, const float* __restrict__ cws,
                                               const float* __restrict__ X, const u32* __restrict__ Xb,
                                               const float* __restrict__ dg,
                                               u32* __restrict__ il1, float* __restrict__ fp1, int N) {
    int t = threadIdx.x;
    int lane = t & 63;
    int r = blockIdx.x * 4 + (t >> 6);
    if (r >= N) return;
    int s = rp[r], e = rp[r + 1];
    float agx = 0.f, agy = 0.f, asx = 0.f, asy = 0.f;
    int j = s;
    for (; j + UN <= e; j += UN) {
        int jb = __builtin_amdgcn_readfirstlane(j);   // wave-uniform -> scalar loads
        int c[UN]; float wg[UN], ws[UN];
#pragma unroll
        for (int u = 0; u < UN; ++u) {
            c[u]  = ci[jb + u];
            wg[u] = cwg[jb + u];
            ws[u] = cws[jb + u];
        }
        u32 pv[UN];
#pragma unroll
        for (int u = 0; u < UN; ++u) pv[u] = Xb[c[u] * 64 + lane];
#pragma unroll
        for (int u = 0; u < UN; ++u) {
            float vx, vy; ubf(pv[u], vx, vy);
            agx = fmaf(wg[u], vx, agx); agy = fmaf(wg[u], vy, agy);
            asx = fmaf(ws[u], vx, asx); asy = fmaf(ws[u], vy, asy);
        }
    }
    for (; j < e; ++j) {
        int jb = __builtin_amdgcn_readfirstlane(j);
        int c = ci[jb];
        float wg = cwg[jb], ws = cws[jb];
        float vx, vy; ubf(Xb[c * 64 + lane], vx, vy);
        agx = fmaf(wg, vx, agx); agy = fmaf(wg, vy, agy);
        asx = fmaf(ws, vx, asx); asy = fmaf(ws, vy, asy);
    }
    float g = dg[r];
    f2 xr = ld2(X + r * DF + lane * 2);
    float gox = (agx + g * xr.x) * g, goy = (agy + g * xr.y) * g;
    float sox = 0.5f * xr.x + 0.5f * asx, soy = 0.5f * xr.y + 0.5f * asy;
    uint2 o = { pbf(gox, goy), pbf(sox, soy) };
    *(uint2*)(il1 + r * 128 + 2 * lane) = o;
    st2(fp1 + r * DF + lane * 2, {sox, soy});
}

// Steps 2,3: one dwordx2 gather per edge serves BOTH towers.
// fpb (optional): compact bf16 mirror of the fp output, for step 4's gathers.
__global__ void __launch_bounds__(256) k_step23(const int* __restrict__ rp, const int* __restrict__ ci,
                                                const float* __restrict__ cwg, const float* __restrict__ cws,
                                                const u32* __restrict__ ils,
                                                const float* __restrict__ sfull,
                                                const float* __restrict__ dg,
                                                u32* __restrict__ ild,
                                                float* __restrict__ sdst,
                                                u32* __restrict__ hsb,
                                                u32* __restrict__ fpb,
                                                const int* __restrict__ mom, int N) {
    int t = threadIdx.x;
    int lane = t & 63;
    int r = blockIdx.x * 4 + (t >> 6);
    if (r >= N) return;
    int s = rp[r], e = rp[r + 1];
    float agx = 0.f, agy = 0.f, asx = 0.f, asy = 0.f;
    int j = s;
    for (; j + UN <= e; j += UN) {
        int jb = __builtin_amdgcn_readfirstlane(j);
        int c[UN]; float wg[UN], ws[UN];
#pragma unroll
        for (int u = 0; u < UN; ++u) {
            c[u]  = ci[jb + u];
            wg[u] = cwg[jb + u];
            ws[u] = cws[jb + u];
        }
        uint2 pv[UN];
#pragma unroll
        for (int u = 0; u < UN; ++u) pv[u] = *(const uint2*)(ils + (size_t)c[u] * 128 + 2 * lane);
#pragma unroll
        for (int u = 0; u < UN; ++u) {
            float gx, gy, sx, sy;
            ubf(pv[u].x, gx, gy);
            ubf(pv[u].y, sx, sy);
            agx = fmaf(wg[u], gx, agx); agy = fmaf(wg[u], gy, agy);
            asx = fmaf(ws[u], sx, asx); asy = fmaf(ws[u], sy, asy);
        }
    }
    for (; j < e; ++j) {
        int jb = __builtin_amdgcn_readfirstlane(j);
        int c = ci[jb];
        float wg = cwg[jb], ws = cws[jb];
        uint2 pv = *(const uint2*)(ils + (size_t)c * 128 + 2 * lane);
        float gx, gy, sx, sy;
        ubf(pv.x, gx, gy);
        ubf(pv.y, sx, sy);
        agx = fmaf(wg, gx, agx); agy = fmaf(wg, gy, agy);
        asx = fmaf(ws, sx, asx); asy = fmaf(ws, sy, asy);
    }
    float g = dg[r];
    float grx, gry; ubf(ils[r * 128 + 2 * lane], grx, gry);
    float gox = (agx + g * grx) * g, goy = (agy + g * gry) * g;
    f2 pvv = ld2(sfull + r * DF + lane * 2);
    float nvx = 0.5f * pvv.x + 0.5f * asx, nvy = 0.5f * pvv.y + 0.5f * asy;
    u32 fppack = pbf(nvx, nvy);
    uint2 o = { pbf(gox, goy), fppack };
    *(uint2*)(ild + r * 128 + 2 * lane) = o;
    st2(sdst + r * DF + lane * 2, {nvx, nvy});
    if (fpb != nullptr) fpb[r * 64 + lane] = fppack;   // compact mirror for step 4
    float ddx = fabsf(pvv.x - nvx), ddy = fabsf(pvv.y - nvy);
    int m = decode_m(mom[0]);
    if (m != 1) { ddx = powf(ddx, (float)m); ddy = powf(ddy, (float)m); }
    hsb[r * 64 + lane] = pbf(ddx, ddy);
}

// Step 4 + attention fused; gathers from the COMPACT fp mirror (full line use).
__global__ void __launch_bounds__(256) k_step4attn(const int* __restrict__ rp, const int* __restrict__ ci,
                                                   const float* __restrict__ cws,
                                                   const u32* __restrict__ il1, const u32* __restrict__ il2,
                                                   const u32* __restrict__ il3,
                                                   const u32* __restrict__ fp3b,
                                                   const float* __restrict__ sfull,
                                                   const u32* __restrict__ s1b, const u32* __restrict__ s2b,
                                                   const float* __restrict__ X, const float* __restrict__ a,
                                                   u32* __restrict__ hpb,
                                                   const int* __restrict__ mom, int N) {
    int t = threadIdx.x;
    int lane = t & 63;
    int r = blockIdx.x * 4 + (t >> 6);
    if (r >= N) return;
    int s = rp[r], e = rp[r + 1];
    float asx = 0.f, asy = 0.f;
    int j = s;
    for (; j + UN <= e; j += UN) {
        int jb = __builtin_amdgcn_readfirstlane(j);
        int c[UN]; float ws[UN];
#pragma unroll
        for (int u = 0; u < UN; ++u) {
            c[u]  = ci[jb + u];
            ws[u] = cws[jb + u];
        }
        u32 pv[UN];
#pragma unroll
        for (int u = 0; u < UN; ++u) pv[u] = fp3b[c[u] * 64 + lane];
#pragma unroll
        for (int u = 0; u < UN; ++u) {
            float sx, sy; ubf(pv[u], sx, sy);
            asx = fmaf(ws[u], sx, asx); asy = fmaf(ws[u], sy, asy);
        }
    }
    for (; j < e; ++j) {
        int jb = __builtin_amdgcn_readfirstlane(j);
        float ws = cws[jb];
        float sx, sy; ubf(fp3b[ci[jb] * 64 + lane], sx, sy);
        asx = fmaf(ws, sx, asx); asy = fmaf(ws, sy, asy);
    }
    f2 pvv = ld2(sfull + r * DF + lane * 2);
    float ddx = fabsf(pvv.x - (0.5f * pvv.x + 0.5f * asx));
    float ddy = fabsf(pvv.y - (0.5f * pvv.y + 0.5f * asy));
    int m = decode_m(mom[0]);
    if (m != 1) { ddx = powf(ddx, (float)m); ddy = powf(ddy, (float)m); }

    float hx[6], hy[6];
    ubf(il1[r * 128 + 2 * lane], hx[0], hy[0]);
    ubf(il2[r * 128 + 2 * lane], hx[1], hy[1]);
    ubf(il3[r * 128 + 2 * lane], hx[2], hy[2]);
    ubf(s1b[r * 64 + lane], hx[3], hy[3]);
    ubf(s2b[r * 64 + lane], hx[4], hy[4]);
    hx[5] = ddx; hy[5] = ddy;
#pragma unroll
    for (int c = 0; c < 3; ++c) {
        hx[c] = hx[c] > 0.f ? hx[c] : NEG * hx[c];
        hy[c] = hy[c] > 0.f ? hy[c] : NEG * hy[c];
    }
    f2 xr = ld2(X + r * DF + lane * 2);
    f2 a1 = ld2(a + lane * 2);
    f2 a2 = ld2(a + DF + lane * 2);
    float part[7];
    part[0] = fmaxf(xr.x, 0.f) * a1.x + fmaxf(xr.y, 0.f) * a1.y;
#pragma unroll
    for (int c = 0; c < 6; ++c)
        part[c + 1] = fmaxf(hx[c], 0.f) * a2.x + fmaxf(hy[c], 0.f) * a2.y;
#pragma unroll
    for (int k = 0; k < 7; ++k) {
        float v = part[k];
#pragma unroll
        for (int mm = 32; mm > 0; mm >>= 1) v += __shfl_xor(v, mm, 64);
        part[k] = v;
    }
    float ev[6], mx = -1e30f;
#pragma unroll
    for (int c = 0; c < 6; ++c) { ev[c] = part[0] + part[c + 1]; mx = fmaxf(mx, ev[c]); }
    float ssum = 0.f;
#pragma unroll
    for (int c = 0; c < 6; ++c) { ev[c] = __expf(ev[c] - mx); ssum += ev[c]; }
    float sc = 1.f / (6.f * ssum);
    float ox = 0.f, oy = 0.f;
#pragma unroll
    for (int c = 0; c < 6; ++c) { ox = fmaf(ev[c], hx[c], ox); oy = fmaf(ev[c], hy[c], oy); }
    hpb[r * 64 + lane] = pbf(ox * sc, oy * sc);
}

// Fused 2-layer MLP via bf16 MFMA (16x16x32). 4 waves/block; wave w owns
// column-tiles {w, w+4} of W1 AND W2 as persistent register B-fragments.
__global__ void __launch_bounds__(256) k_mlp2x(const u32* __restrict__ hpb,
                                               const float* __restrict__ W1, const float* __restrict__ b1,
                                               const float* __restrict__ W2, const float* __restrict__ b2,
                                               float* __restrict__ out, int N, int NT) {
    __shared__ unsigned short ylds[16][136];
    int t = threadIdx.x, lane = t & 63, wv = t >> 6;
    int n15 = lane & 15, quad = lane >> 4;
    s8v w1f[2][4], w2f[2][4];
    float bias1[2], bias2[2];
#pragma unroll
    for (int i = 0; i < 2; ++i) {
        int ct = wv + 4 * i;
        int rw = ct * 16 + n15;
#pragma unroll
        for (int q = 0; q < 4; ++q) {
            w1f[i][q] = pack8(W1 + rw * DF + q * 32 + quad * 8);
            w2f[i][q] = pack8(W2 + rw * DF + q * 32 + quad * 8);
        }
        bias1[i] = b1[rw];
        bias2[i] = b2[rw];
    }
    for (int tile = blockIdx.x; tile < NT; tile += gridDim.x) {
        int row0 = tile * 16;
        int rA = row0 + n15; if (rA >= N) rA = N - 1;
        s8v a1[4];
        const u32* src = hpb + (size_t)rA * 64;
#pragma unroll
        for (int q = 0; q < 4; ++q) a1[q] = load8p(src + q * 16 + quad * 4);
        f4v acc0 = {0.f, 0.f, 0.f, 0.f}, acc1 = {0.f, 0.f, 0.f, 0.f};
#pragma unroll
        for (int q = 0; q < 4; ++q) {
            acc0 = __builtin_amdgcn_mfma_f32_16x16x32_bf16(a1[q], w1f[0][q], acc0, 0, 0, 0);
            acc1 = __builtin_amdgcn_mfma_f32_16x16x32_bf16(a1[q], w1f[1][q], acc1, 0, 0, 0);
        }
        __syncthreads();
#pragma unroll
        for (int i = 0; i < 2; ++i) {
            int cb = (wv + 4 * i) * 16 + n15;
#pragma unroll
            for (int reg = 0; reg < 4; ++reg) {
                float v = (i == 0 ? acc0[reg] : acc1[reg]) + bias1[i];
                v = v > 0.f ? v : NEG * v;
                ylds[quad * 4 + reg][cb] = f2bf(v);
            }
        }
        __syncthreads();
        s8v a2[4];
#pragma unroll
        for (int q = 0; q < 4; ++q)
            a2[q] = *(const s8v*)&ylds[n15][q * 32 + quad * 8];
        f4v o0 = {0.f, 0.f, 0.f, 0.f}, o1 = {0.f, 0.f, 0.f, 0.f};
#pragma unroll
        for (int q = 0; q < 4; ++q) {
            o0 = __builtin_amdgcn_mfma_f32_16x16x32_bf16(a2[q], w2f[0][q], o0, 0, 0, 0);
            o1 = __builtin_amdgcn_mfma_f32_16x16x32_bf16(a2[q], w2f[1][q], o1, 0, 0, 0);
        }
#pragma unroll
        for (int i = 0; i < 2; ++i) {
            int cb = (wv + 4 * i) * 16 + n15;
#pragma unroll
            for (int reg = 0; reg < 4; ++reg) {
                int rr = row0 + quad * 4 + reg;
                if (rr < N) {
                    float v = (i == 0 ? o0[reg] : o1[reg]) + bias2[i];
                    out[(size_t)rr * DF + cb] = v > 0.f ? v : NEG * v;
                }
            }
        }
    }
}

extern "C" void kernel_launch(void* const* d_in, const int* in_sizes, int n_in,
                              void* d_out, int out_size, void* d_ws, size_t ws_size,
                              hipStream_t stream) {
    const float* X  = (const float*)d_in[0];
    const int*   ei = (const int*)d_in[1];
    const float* ew = (const float*)d_in[2];
    const float* W1 = (const float*)d_in[3];
    const float* b1 = (const float*)d_in[4];
    const float* W2 = (const float*)d_in[5];
    const float* b2 = (const float*)d_in[6];
    const float* a  = (const float*)d_in[7];
    const int*  mom = (const int*)d_in[8];

    const int N = in_sizes[0] / DF;
    const int E = in_sizes[2];
    const int* row = ei;
    const int* col = ei + E;
    const size_t ND = (size_t)N * DF;
    const size_t ND2 = ND / 2;

    char* p = (char*)d_ws;
    auto alloc = [&](size_t bytes) -> void* {
        char* r = p;
        p += (bytes + 255) & ~(size_t)255;
        return (void*)r;
    };
    float* P   = (float*)alloc(ND * 4);     // fp state (f32)
    float* Q   = (float*)alloc(ND * 4);     // fp state (f32)
    u32*   Xb  = (u32*)alloc(ND2 * 4);
    u32*   IL1 = (u32*)alloc(ND * 4);       // interleaved {G, fp} bf16 mirrors
    u32*   IL2 = (u32*)alloc(ND * 4);
    u32*   IL3 = (u32*)alloc(ND * 4);
    u32*   FP3 = (u32*)alloc(ND2 * 4);      // compact fp3 bf16 (step4 gathers)
    u32*   S1b = (u32*)alloc(ND2 * 4);
    u32*   S2b = (u32*)alloc(ND2 * 4);
    u32*   Qb  = (u32*)alloc(ND2 * 4);      // h' packed bf16
    float* cdeg = (float*)alloc((size_t)N * 4);
    int*   rcnt = (int*)alloc((size_t)N * 4);
    float* dg   = (float*)alloc((size_t)N * 4);
    float* dinv = (float*)alloc((size_t)N * 4);
    int*   rp   = (int*)alloc((size_t)(N + 1) * 4);
    int*   cur  = (int*)alloc((size_t)N * 4);
    int*   bsum = (int*)alloc((size_t)256 * 4);
    int*   ci   = (int*)alloc((size_t)E * 4);
    float* cwg  = (float*)alloc((size_t)E * 4);
    float* cws  = (float*)alloc((size_t)E * 4);

    if ((size_t)(p - (char*)d_ws) > ws_size) {
        k_sentinel<<<(out_size + 255) / 256, 256, 0, stream>>>((float*)d_out, out_size);
        return;
    }

    hipMemsetAsync(cdeg, 0, (size_t)N * 4, stream);
    hipMemsetAsync(rcnt, 0, (size_t)N * 4, stream);

    int eb = (E + 255) / 256;
    k_deg<<<eb, 256, 0, stream>>>(row, col, ew, cdeg, rcnt, E);
    k_derive<<<(N + 255) / 256, 256, 0, stream>>>(cdeg, dg, dinv, N);
    k_xcast<<<(int)((ND2 + 255) / 256), 256, 0, stream>>>(X, Xb, (int)ND2);

    int SB = (N + 1023) / 1024;
    k_scan1<<<SB, 256, 0, stream>>>(rcnt, rp, bsum, N);
    k_scan2<<<1, 64, 0, stream>>>(bsum, SB);
    k_scan3<<<(N + 255) / 256, 256, 0, stream>>>(bsum, rp, cur, N, SB);

    k_scatter<<<eb, 256, 0, stream>>>(row, col, ew, dg, dinv, cur, ci, cwg, cws, E);

    int rb = (N + 3) / 4;
    k_step1<<<rb, 256, 0, stream>>>(rp, ci, cwg, cws, X, Xb, dg, IL1, P, N);
    // Step 2: no compact mirror needed
    k_step23<<<rb, 256, 0, stream>>>(rp, ci, cwg, cws, IL1, P, dg, IL2, Q, S1b, (u32*)nullptr, mom, N);
    // Step 3: emit compact FP3 for step 4
    k_step23<<<rb, 256, 0, stream>>>(rp, ci, cwg, cws, IL2, Q, dg, IL3, P, S2b, FP3, mom, N);
    k_step4attn<<<rb, 256, 0, stream>>>(rp, ci, cws, IL1, IL2, IL3, FP3, P, S1b, S2b, X, a, Qb, mom, N);

    // Fused MFMA MLP: Qb -> d_out
    int NT = (N + 15) / 16;
    int gb = NT < 1024 ? NT : 1024;
    k_mlp2x<<<gb, 256, 0, stream>>>(Qb, W1, b1, W2, b2, (float*)d_out, N, NT);
}